// Round 3
// baseline (2853.867 us; speedup 1.0000x reference)
//
#include <hip/hip_runtime.h>
#include <math.h>

#define NB 64
#define NN 207
#define NT 48
#define NF 6
#define NH 64
#define NSEQ (NB*NN)          // 13248 = 207 * 64 exactly
#define TPLANE (NSEQ*NH)      // floats per t-plane in seqx [t][seq][64]

// ---------------- GCN (both layers fused, one block per (b,t)) ----------------
#define H1S 212
#define GCN_LDS_FLOATS (64*H1S + 64*64 + NN*NF + NF*64 + 64 + 64 + 64 + 64)

__global__ __launch_bounds__(256, 2) void gcn_kernel(
    const float* __restrict__ x, const float* __restrict__ W1, const float* __restrict__ b1,
    const float* __restrict__ W2, const float* __restrict__ b2, float* __restrict__ seqx)
{
  extern __shared__ float sm[];
  float* h1T = sm;                      // [64 feat][212]
  float* W2s = h1T + 64*H1S;            // [64 k][64 h]
  float* xs  = W2s + 64*64;             // [207][6]
  float* W1s = xs  + NN*NF;             // [6][64]
  float* b1s = W1s + NF*64;
  float* b2s = b1s + 64;
  float* S1  = b2s + 64;
  float* S2  = S1  + 64;

  const int tid = threadIdx.x;
  const int t = blockIdx.x, b = blockIdx.y;
  const float inv = 1.0f/208.0f;

  for (int i=tid;i<64*64;i+=256) W2s[i]=W2[i];
  for (int i=tid;i<NF*64;i+=256) W1s[i]=W1[i];
  if (tid<64){ b1s[tid]=b1[tid]; b2s[tid]=b2[tid]; S1[tid]=0.f; S2[tid]=0.f; }
  {
    const float* xb = x + (size_t)b*NN*NT*NF + (size_t)t*NF;
    for (int i=tid;i<NN*NF;i+=256){ int n=i/NF, f=i-n*NF; xs[i] = xb[(size_t)n*NT*NF + f]; }
  }
  for (int i=tid;i<64*5;i+=256){ int h=i/5, c=i-h*5; h1T[h*H1S + NN + c] = 0.f; }
  __syncthreads();

  #pragma unroll 1
  for (int p=0;p<4;p++){
    int tile = p*256 + tid;
    if (tile < 832){
      int nt = tile>>4, ht = tile&15;
      #pragma unroll
      for (int i=0;i<4;i++){
        int n = 4*nt+i;
        if (n < NN){
          float a0=0.f,a1=0.f,a2=0.f,a3=0.f;
          #pragma unroll
          for (int f=0;f<NF;f++){
            float xv = xs[n*NF+f];
            float4 wv = *(const float4*)&W1s[f*64 + 4*ht];
            a0 += xv*wv.x; a1 += xv*wv.y; a2 += xv*wv.z; a3 += xv*wv.w;
          }
          h1T[(4*ht+0)*H1S+n]=a0; h1T[(4*ht+1)*H1S+n]=a1;
          h1T[(4*ht+2)*H1S+n]=a2; h1T[(4*ht+3)*H1S+n]=a3;
        }
      }
    }
  }
  __syncthreads();

  {
    int h = tid & 63, grp = tid >> 6;
    float ps = 0.f;
    for (int n=grp; n<NN; n+=4) ps += h1T[h*H1S+n];
    atomicAdd(&S1[h], ps);
  }
  __syncthreads();

  for (int e=tid; e<64*NN; e+=256){
    int h = e/NN, n = e - h*NN;
    float v = (h1T[h*H1S+n] + S1[h])*inv + b1s[h];
    h1T[h*H1S+n] = v>0.f ? v : 0.f;
  }
  __syncthreads();

  float acc[4][16];
  #pragma unroll
  for (int p=0;p<4;p++){
    #pragma unroll
    for (int e=0;e<16;e++) acc[p][e]=0.f;
    int tile = p*256 + tid;
    if (tile < 832){
      int nt = tile>>4, ht = tile&15;
      const float* arow = h1T + 4*nt;
      const float* wrow = W2s + 4*ht;
      #pragma unroll 4
      for (int k=0;k<64;k++){
        float4 a = *(const float4*)(arow + k*H1S);
        float4 w = *(const float4*)(wrow + k*64);
        acc[p][ 0] += a.x*w.x; acc[p][ 1] += a.x*w.y; acc[p][ 2] += a.x*w.z; acc[p][ 3] += a.x*w.w;
        acc[p][ 4] += a.y*w.x; acc[p][ 5] += a.y*w.y; acc[p][ 6] += a.y*w.z; acc[p][ 7] += a.y*w.w;
        acc[p][ 8] += a.z*w.x; acc[p][ 9] += a.z*w.y; acc[p][10] += a.z*w.z; acc[p][11] += a.z*w.w;
        acc[p][12] += a.w*w.x; acc[p][13] += a.w*w.y; acc[p][14] += a.w*w.z; acc[p][15] += a.w*w.w;
      }
      #pragma unroll
      for (int j=0;j<4;j++){
        float ps = acc[p][j] + acc[p][4+j] + acc[p][8+j] + acc[p][12+j];
        atomicAdd(&S2[4*ht+j], ps);
      }
    }
  }
  __syncthreads();

  // h2 -> seqx[t][b*207+n][h]  (contiguous 207*64-float region per block)
  float* outp = seqx + (size_t)t*TPLANE + (size_t)(b*NN)*NH;
  #pragma unroll
  for (int p=0;p<4;p++){
    int tile = p*256 + tid;
    if (tile < 832){
      int nt = tile>>4, ht = tile&15;
      #pragma unroll
      for (int i=0;i<4;i++){
        int n = 4*nt+i;
        if (n < NN){
          float4 o;
          float v0 = (acc[p][i*4+0] + S2[4*ht+0])*inv + b2s[4*ht+0];
          float v1 = (acc[p][i*4+1] + S2[4*ht+1])*inv + b2s[4*ht+1];
          float v2 = (acc[p][i*4+2] + S2[4*ht+2])*inv + b2s[4*ht+2];
          float v3 = (acc[p][i*4+3] + S2[4*ht+3])*inv + b2s[4*ht+3];
          o.x = v0>0.f?v0:0.f; o.y = v1>0.f?v1:0.f; o.z = v2>0.f?v2:0.f; o.w = v3>0.f?v3:0.f;
          *(float4*)&outp[(size_t)n*NH + 4*ht] = o;
        }
      }
    }
  }
}

// ---------------- LSTM v3: lane = sequence, weights via scalar pipe ----------------
// 207 blocks x 256 threads. Lane s = seq (64 seqs/block); wave w owns gate dims
// d in [16w, 16w+16) x 4 types -> acc[16][4] and c[16] never leave registers.
// Weight addresses are wave-uniform (readfirstlane) -> s_load + v_fmac(sgpr,vgpr).
// x/h live in LDS rows of stride 65 (bank-conflict-free b32 reads).
#define XHS3 65
#define LSTM3_LDS_FLOATS (64*XHS3*2)    // 33280 B

__device__ __forceinline__ float fsig(float x){
  return 1.0f/(1.0f + __expf(-x));
}
__device__ __forceinline__ float ftanh(float x){
  x = fminf(15.0f, fmaxf(-15.0f, x));
  float e = __expf(2.0f*x);
  return (e - 1.0f)/(e + 1.0f);
}

__global__ __launch_bounds__(256, 1) void lstm3_kernel(
    const float* __restrict__ seqx, const float* __restrict__ Wih, const float* __restrict__ Whh,
    const float* __restrict__ bih, const float* __restrict__ bhh,
    const float* __restrict__ Wfc, const float* __restrict__ bfc, float* __restrict__ out)
{
  extern __shared__ float sm[];
  float* xb = sm;               // [64][65]
  float* hb = xb + 64*XHS3;     // [64][65]

  const int tid = threadIdx.x;
  const int s = tid & 63;
  const int w = __builtin_amdgcn_readfirstlane(tid >> 6);  // uniform wave id
  const int d0 = w * 16;
  const int s0 = blockIdx.x * 64;

  // zero h
  for (int i=tid;i<64*XHS3;i+=256) hb[i]=0.f;
  // stage x for t=0: 4096 floats contiguous at seqx[0][s0*64]
  {
    const float4* gp = (const float4*)(seqx + (size_t)s0*NH);
    #pragma unroll
    for (int p=0;p<4;p++){
      int f4 = p*256 + tid;                  // [0,1024)
      float4 v = gp[f4];
      int ss = f4 >> 4, k4 = (f4 & 15) * 4;
      float* dp = xb + ss*XHS3 + k4;
      dp[0]=v.x; dp[1]=v.y; dp[2]=v.z; dp[3]=v.w;
    }
  }

  // per-thread (lane-uniform) bias for its 16 d x 4 types
  float bs[16][4];
  #pragma unroll
  for (int d=0; d<16; d++){
    #pragma unroll
    for (int ty=0; ty<4; ty++){
      int r = ty*64 + d0 + d;
      bs[d][ty] = bih[r] + bhh[r];
    }
  }

  float c[16];
  #pragma unroll
  for (int d=0; d<16; d++) c[d]=0.f;

  __syncthreads();

  for (int t=0; t<NT; t++){
    float acc[16][4];
    #pragma unroll
    for (int d=0; d<16; d++){
      #pragma unroll
      for (int ty=0; ty<4; ty++) acc[d][ty] = bs[d][ty];
    }

    // 4 k-chunks of 32: kc 0,1 = x-part (W_ih), kc 2,3 = h-part (W_hh)
    #pragma unroll 1
    for (int kc=0; kc<4; kc++){
      const float* src  = (kc<2) ? xb  : hb;
      const float* Wsel = (kc<2) ? Wih : Whh;
      const int k0 = (kc & 1) * 32;

      float v[32];
      const float* sp = src + s*XHS3 + k0;
      #pragma unroll
      for (int j=0;j<32;j++) v[j] = sp[j];   // lane-distinct, conflict-free b32

      #pragma unroll 2
      for (int d=0; d<16; d++){
        #pragma unroll
        for (int ty=0; ty<4; ty++){
          const float* wr = Wsel + ((ty<<6) + d0 + d)*64 + k0;  // wave-uniform
          #pragma unroll
          for (int j=0;j<32;j++) acc[d][ty] += v[j] * wr[j];
        }
      }
    }
    __syncthreads();   // all xb/hb reads done

    // gate nonlinearity + state update, all in registers
    #pragma unroll
    for (int d=0; d<16; d++){
      float ig = fsig(acc[d][0]);
      float fg = fsig(acc[d][1]);
      float gt = ftanh(acc[d][2]);
      float og = fsig(acc[d][3]);
      float cc = fg*c[d] + ig*gt;
      c[d] = cc;
      hb[s*XHS3 + d0 + d] = og*ftanh(cc);
    }

    // stage x for t+1 (contiguous 16 KB)
    if (t+1 < NT){
      const float4* gp = (const float4*)(seqx + (size_t)(t+1)*TPLANE + (size_t)s0*NH);
      #pragma unroll
      for (int p=0;p<4;p++){
        int f4 = p*256 + tid;
        float4 v = gp[f4];
        int ss = f4 >> 4, k4 = (f4 & 15) * 4;
        float* dp = xb + ss*XHS3 + k4;
        dp[0]=v.x; dp[1]=v.y; dp[2]=v.z; dp[3]=v.w;
      }
    }
    __syncthreads();   // h/x ready for next step
  }

  // epilogue: out[seq] = h_T . W_fc + b_fc   (wave 0 handles all 64 seqs)
  if (tid < 64){
    float a = bfc[0];
    const float* hp = hb + tid*XHS3;
    #pragma unroll 8
    for (int k=0;k<64;k++) a += hp[k]*Wfc[k];
    out[s0+tid] = a;
  }
}

extern "C" void kernel_launch(void* const* d_in, const int* in_sizes, int n_in,
                              void* d_out, int out_size, void* d_ws, size_t ws_size,
                              hipStream_t stream) {
  const float* x   = (const float*)d_in[0];
  // d_in[1], d_in[2] (N1, N2): structurally dead — sigmoid(N1@N2)>0 is all-ones.
  const float* W1  = (const float*)d_in[3];
  const float* b1  = (const float*)d_in[4];
  const float* W2  = (const float*)d_in[5];
  const float* b2  = (const float*)d_in[6];
  const float* Wih = (const float*)d_in[7];
  const float* Whh = (const float*)d_in[8];
  const float* bih = (const float*)d_in[9];
  const float* bhh = (const float*)d_in[10];
  const float* Wfc = (const float*)d_in[11];
  const float* bfc = (const float*)d_in[12];
  float* seqx = (float*)d_ws;           // [48 t][13248 seq][64 h] fp32 = 162.8 MB
  float* out  = (float*)d_out;

  const int gcn_lds  = GCN_LDS_FLOATS  * 4;
  const int lstm_lds = LSTM3_LDS_FLOATS * 4;   // 33280 B
  hipFuncSetAttribute((const void*)gcn_kernel,   hipFuncAttributeMaxDynamicSharedMemorySize, gcn_lds);
  hipFuncSetAttribute((const void*)lstm3_kernel, hipFuncAttributeMaxDynamicSharedMemorySize, lstm_lds);

  gcn_kernel<<<dim3(NT, NB), 256, gcn_lds, stream>>>(x, W1, b1, W2, b2, seqx);
  lstm3_kernel<<<NSEQ/64, 256, lstm_lds, stream>>>(seqx, Wih, Whh, bih, bhh, Wfc, bfc, out);
}

// Round 4
// 655.328 us; speedup vs baseline: 4.3549x; 4.3549x over previous
//
#include <hip/hip_runtime.h>
#include <math.h>

#define NB 64
#define NN 207
#define NT 48
#define NF 6
#define NH 64
#define NSEQ (NB*NN)          // 13248 = 207 * 64 exactly
#define TPLANE (NSEQ*NH)      // elements per t-plane in seqx [t][seq][64]

typedef short bf8_t __attribute__((ext_vector_type(8)));
typedef float f4_t  __attribute__((ext_vector_type(4)));
typedef unsigned short ushort;

__device__ __forceinline__ ushort bf16h(float x){
  unsigned int u = __float_as_uint(x);
  return (ushort)((u + 0x7FFF + ((u>>16)&1)) >> 16);
}
__device__ __forceinline__ float bf16f(ushort h){
  return __uint_as_float((unsigned int)h << 16);
}

// ---------------- GCN (both layers fused, one block per (b,t)) ----------------
#define H1S 212
#define GCN_LDS_FLOATS (64*H1S + 64*64 + NN*NF + NF*64 + 64 + 64 + 64 + 64)

__global__ __launch_bounds__(256, 2) void gcn_kernel(
    const float* __restrict__ x, const float* __restrict__ W1, const float* __restrict__ b1,
    const float* __restrict__ W2, const float* __restrict__ b2,
    ushort* __restrict__ sx_hi, ushort* __restrict__ sx_lo)
{
  extern __shared__ float sm[];
  float* h1T = sm;                      // [64 feat][212]
  float* W2s = h1T + 64*H1S;            // [64 k][64 h]
  float* xs  = W2s + 64*64;             // [207][6]
  float* W1s = xs  + NN*NF;             // [6][64]
  float* b1s = W1s + NF*64;
  float* b2s = b1s + 64;
  float* S1  = b2s + 64;
  float* S2  = S1  + 64;

  const int tid = threadIdx.x;
  const int t = blockIdx.x, b = blockIdx.y;
  const float inv = 1.0f/208.0f;

  for (int i=tid;i<64*64;i+=256) W2s[i]=W2[i];
  for (int i=tid;i<NF*64;i+=256) W1s[i]=W1[i];
  if (tid<64){ b1s[tid]=b1[tid]; b2s[tid]=b2[tid]; S1[tid]=0.f; S2[tid]=0.f; }
  {
    const float* xb = x + (size_t)b*NN*NT*NF + (size_t)t*NF;
    for (int i=tid;i<NN*NF;i+=256){ int n=i/NF, f=i-n*NF; xs[i] = xb[(size_t)n*NT*NF + f]; }
  }
  for (int i=tid;i<64*5;i+=256){ int h=i/5, c=i-h*5; h1T[h*H1S + NN + c] = 0.f; }
  __syncthreads();

  #pragma unroll 1
  for (int p=0;p<4;p++){
    int tile = p*256 + tid;
    if (tile < 832){
      int nt = tile>>4, ht = tile&15;
      #pragma unroll
      for (int i=0;i<4;i++){
        int n = 4*nt+i;
        if (n < NN){
          float a0=0.f,a1=0.f,a2=0.f,a3=0.f;
          #pragma unroll
          for (int f=0;f<NF;f++){
            float xv = xs[n*NF+f];
            float4 wv = *(const float4*)&W1s[f*64 + 4*ht];
            a0 += xv*wv.x; a1 += xv*wv.y; a2 += xv*wv.z; a3 += xv*wv.w;
          }
          h1T[(4*ht+0)*H1S+n]=a0; h1T[(4*ht+1)*H1S+n]=a1;
          h1T[(4*ht+2)*H1S+n]=a2; h1T[(4*ht+3)*H1S+n]=a3;
        }
      }
    }
  }
  __syncthreads();

  {
    int h = tid & 63, grp = tid >> 6;
    float ps = 0.f;
    for (int n=grp; n<NN; n+=4) ps += h1T[h*H1S+n];
    atomicAdd(&S1[h], ps);
  }
  __syncthreads();

  for (int e=tid; e<64*NN; e+=256){
    int h = e/NN, n = e - h*NN;
    float v = (h1T[h*H1S+n] + S1[h])*inv + b1s[h];
    h1T[h*H1S+n] = v>0.f ? v : 0.f;
  }
  __syncthreads();

  float acc[4][16];
  #pragma unroll
  for (int p=0;p<4;p++){
    #pragma unroll
    for (int e=0;e<16;e++) acc[p][e]=0.f;
    int tile = p*256 + tid;
    if (tile < 832){
      int nt = tile>>4, ht = tile&15;
      const float* arow = h1T + 4*nt;
      const float* wrow = W2s + 4*ht;
      #pragma unroll 4
      for (int k=0;k<64;k++){
        float4 a = *(const float4*)(arow + k*H1S);
        float4 w = *(const float4*)(wrow + k*64);
        acc[p][ 0] += a.x*w.x; acc[p][ 1] += a.x*w.y; acc[p][ 2] += a.x*w.z; acc[p][ 3] += a.x*w.w;
        acc[p][ 4] += a.y*w.x; acc[p][ 5] += a.y*w.y; acc[p][ 6] += a.y*w.z; acc[p][ 7] += a.y*w.w;
        acc[p][ 8] += a.z*w.x; acc[p][ 9] += a.z*w.y; acc[p][10] += a.z*w.z; acc[p][11] += a.z*w.w;
        acc[p][12] += a.w*w.x; acc[p][13] += a.w*w.y; acc[p][14] += a.w*w.z; acc[p][15] += a.w*w.w;
      }
      #pragma unroll
      for (int j=0;j<4;j++){
        float ps = acc[p][j] + acc[p][4+j] + acc[p][8+j] + acc[p][12+j];
        atomicAdd(&S2[4*ht+j], ps);
      }
    }
  }
  __syncthreads();

  // h2 = relu(...) -> split to bf16 hi/lo planes at [t][b*207+n][h]
  const size_t obase = (size_t)t*TPLANE + (size_t)(b*NN)*NH;
  #pragma unroll
  for (int p=0;p<4;p++){
    int tile = p*256 + tid;
    if (tile < 832){
      int nt = tile>>4, ht = tile&15;
      #pragma unroll
      for (int i=0;i<4;i++){
        int n = 4*nt+i;
        if (n < NN){
          float v[4];
          #pragma unroll
          for (int j=0;j<4;j++){
            float vv = (acc[p][i*4+j] + S2[4*ht+j])*inv + b2s[4*ht+j];
            v[j] = vv>0.f ? vv : 0.f;
          }
          ushort4 hi, lo;
          hi.x = bf16h(v[0]); lo.x = bf16h(v[0]-bf16f(hi.x));
          hi.y = bf16h(v[1]); lo.y = bf16h(v[1]-bf16f(hi.y));
          hi.z = bf16h(v[2]); lo.z = bf16h(v[2]-bf16f(hi.z));
          hi.w = bf16h(v[3]); lo.w = bf16h(v[3]-bf16f(hi.w));
          size_t off = obase + (size_t)n*NH + 4*ht;
          *(ushort4*)&sx_hi[off] = hi;
          *(ushort4*)&sx_lo[off] = lo;
        }
      }
    }
  }
}

// ---------------- LSTM v4: split-bf16 MFMA, weights register-resident ----------------
// 207 blocks x 256 threads (4 waves). Wave w owns gate dims d in [16w,16w+16) x 4 types.
// B-fragments (W^T, hi+lo) persist in VGPRs. X pre-split by GCN into bf16 hi/lo planes;
// H split by producer lane into LDS planes laid out in exact A-fragment order.
#define XW 72   // padded bf16 row stride: 144B rows -> 16B aligned, 2-way banks (free)

__device__ __forceinline__ float fsig(float x){
  return 1.0f/(1.0f + __expf(-x));
}
__device__ __forceinline__ float ftanh(float x){
  x = fminf(15.0f, fmaxf(-15.0f, x));
  float e = __expf(2.0f*x);
  return (e - 1.0f)/(e + 1.0f);
}

__global__ __launch_bounds__(256, 1) void lstm4_kernel(
    const ushort* __restrict__ sx_hi, const ushort* __restrict__ sx_lo,
    const float* __restrict__ Wih, const float* __restrict__ Whh,
    const float* __restrict__ bih, const float* __restrict__ bhh,
    const float* __restrict__ Wfc, const float* __restrict__ bfc, float* __restrict__ out)
{
  __shared__ ushort lds[4*64*XW];      // xh, xl, hh, hl  (36864 B)
  ushort* xh = lds;
  ushort* xl = xh + 64*XW;
  ushort* hh = xl + 64*XW;
  ushort* hl = hh + 64*XW;

  const int tid = threadIdx.x;
  const int l = tid & 63;
  const int w = __builtin_amdgcn_readfirstlane(tid >> 6);
  const int col = l & 15, q = l >> 4;
  const int d0 = w*16;
  const int s0 = blockIdx.x * 64;

  // ---- stage weight fragments into registers (hi+lo), once ----
  // B[k][n] for tile ty, k-chunk kc: lane holds W[r = ty*64 + d0 + col][kg = kc*32 + q*8 + j]
  bf8_t Bh[4][4], Bl[4][4];
  #pragma unroll
  for (int mat=0; mat<2; mat++){
    const float* W = mat ? Whh : Wih;
    #pragma unroll
    for (int ty=0; ty<4; ty++){
      #pragma unroll
      for (int kc2=0; kc2<2; kc2++){
        const float* wp = W + (size_t)(ty*64 + d0 + col)*64 + kc2*32 + q*8;
        bf8_t ph, pl;
        #pragma unroll
        for (int j=0;j<8;j++){
          float wv = wp[j];
          ushort hb = bf16h(wv);
          ph[j] = (short)hb;
          pl[j] = (short)bf16h(wv - bf16f(hb));
        }
        Bh[ty][mat*2+kc2] = ph;
        Bl[ty][mat*2+kc2] = pl;
      }
    }
  }

  // zero h planes (hh & hl contiguous), stage X(0)
  for (int i=tid;i<2*64*XW;i+=256) hh[i]=0;
  {
    const int ss = tid>>2, ch = tid&3;
    size_t base = (size_t)(s0+ss)*64 + ch*16;
    const float4* gh = (const float4*)(sx_hi + base);
    const float4* gl = (const float4*)(sx_lo + base);
    float4 a0=gh[0], a1=gh[1], b0=gl[0], b1=gl[1];
    *(float4*)(xh + ss*XW + ch*16)     = a0;
    *(float4*)(xh + ss*XW + ch*16 + 8) = a1;
    *(float4*)(xl + ss*XW + ch*16)     = b0;
    *(float4*)(xl + ss*XW + ch*16 + 8) = b1;
  }

  float bias[4];
  #pragma unroll
  for (int ty=0;ty<4;ty++){
    int r = ty*64 + d0 + col;
    bias[ty] = bih[r] + bhh[r];
  }
  float c[16];
  #pragma unroll
  for (int i=0;i<16;i++) c[i]=0.f;

  __syncthreads();

  const int ss = tid>>2, ch = tid&3;
  const int d = d0 + col;

  for (int t=0; t<NT; t++){
    f4_t acc[4][4];
    #pragma unroll
    for (int mt=0;mt<4;mt++)
      #pragma unroll
      for (int ty=0;ty<4;ty++){
        f4_t z; z[0]=bias[ty]; z[1]=bias[ty]; z[2]=bias[ty]; z[3]=bias[ty];
        acc[mt][ty]=z;
      }

    // prefetch X(t+1) to registers (lands during MFMA phase)
    float4 px0,px1,px2,px3;
    const bool pf = (t+1 < NT);
    if (pf){
      size_t base = (size_t)(t+1)*TPLANE + (size_t)(s0+ss)*64 + ch*16;
      const float4* gh = (const float4*)(sx_hi + base);
      const float4* gl = (const float4*)(sx_lo + base);
      px0=gh[0]; px1=gh[1]; px2=gl[0]; px3=gl[1];
    }

    // ---- MFMA phase: kc 0,1 = X-part, kc 2,3 = H-part ----
    #pragma unroll
    for (int kc=0;kc<4;kc++){
      const ushort* srch = (kc<2)? xh : hh;
      const ushort* srcl = (kc<2)? xl : hl;
      const int ko = (kc&1)*32 + q*8;
      bf8_t ah[4], al[4];
      #pragma unroll
      for (int mt=0;mt<4;mt++){
        ah[mt] = *(const bf8_t*)(srch + (mt*16+col)*XW + ko);
        al[mt] = *(const bf8_t*)(srcl + (mt*16+col)*XW + ko);
      }
      #pragma unroll
      for (int mt=0;mt<4;mt++){
        #pragma unroll
        for (int ty=0;ty<4;ty++){
          acc[mt][ty] = __builtin_amdgcn_mfma_f32_16x16x32_bf16(ah[mt], Bh[ty][kc], acc[mt][ty], 0,0,0);
          acc[mt][ty] = __builtin_amdgcn_mfma_f32_16x16x32_bf16(al[mt], Bh[ty][kc], acc[mt][ty], 0,0,0);
          acc[mt][ty] = __builtin_amdgcn_mfma_f32_16x16x32_bf16(ah[mt], Bl[ty][kc], acc[mt][ty], 0,0,0);
        }
      }
    }
    __syncthreads();   // all xh/xl/hh/hl reads complete

    // write prefetched X(t+1)
    if (pf){
      *(float4*)(xh + ss*XW + ch*16)     = px0;
      *(float4*)(xh + ss*XW + ch*16 + 8) = px1;
      *(float4*)(xl + ss*XW + ch*16)     = px2;
      *(float4*)(xl + ss*XW + ch*16 + 8) = px3;
    }

    // ---- gate nonlinearity + state update (all in this lane's registers) ----
    #pragma unroll
    for (int mt=0;mt<4;mt++){
      #pragma unroll
      for (int r=0;r<4;r++){
        const int s = mt*16 + q*4 + r;
        float gi = acc[mt][0][r], gf = acc[mt][1][r], gg = acc[mt][2][r], go = acc[mt][3][r];
        float ig = fsig(gi), fg = fsig(gf), gt = ftanh(gg), og = fsig(go);
        float cc = fg*c[mt*4+r] + ig*gt;
        c[mt*4+r] = cc;
        float hv = og*ftanh(cc);
        if (t != NT-1){
          ushort hb = bf16h(hv);
          hh[s*XW + d] = hb;
          hl[s*XW + d] = bf16h(hv - bf16f(hb));
        } else {
          ((float*)lds)[s*68 + d] = hv;   // final h in fp32 (reuses xh/xl space)
        }
      }
    }
    __syncthreads();
  }

  // epilogue: out[seq] = h_T . W_fc + b_fc
  if (tid < 64){
    const float* hf = (const float*)lds;
    float a = bfc[0];
    #pragma unroll 8
    for (int k=0;k<64;k++) a += hf[tid*68+k]*Wfc[k];
    out[s0+tid] = a;
  }
}

extern "C" void kernel_launch(void* const* d_in, const int* in_sizes, int n_in,
                              void* d_out, int out_size, void* d_ws, size_t ws_size,
                              hipStream_t stream) {
  const float* x   = (const float*)d_in[0];
  // d_in[1], d_in[2] (N1, N2): structurally dead — sigmoid(N1@N2)>0 is all-ones.
  const float* W1  = (const float*)d_in[3];
  const float* b1  = (const float*)d_in[4];
  const float* W2  = (const float*)d_in[5];
  const float* b2  = (const float*)d_in[6];
  const float* Wih = (const float*)d_in[7];
  const float* Whh = (const float*)d_in[8];
  const float* bih = (const float*)d_in[9];
  const float* bhh = (const float*)d_in[10];
  const float* Wfc = (const float*)d_in[11];
  const float* bfc = (const float*)d_in[12];

  ushort* sx_hi = (ushort*)d_ws;                         // [48][13248][64] bf16 hi (81.4 MB)
  ushort* sx_lo = sx_hi + (size_t)NT*TPLANE;             // [48][13248][64] bf16 lo (81.4 MB)
  float*  out   = (float*)d_out;

  const int gcn_lds = GCN_LDS_FLOATS * 4;
  hipFuncSetAttribute((const void*)gcn_kernel, hipFuncAttributeMaxDynamicSharedMemorySize, gcn_lds);

  gcn_kernel<<<dim3(NT, NB), 256, gcn_lds, stream>>>(x, W1, b1, W2, b2, sx_hi, sx_lo);
  lstm4_kernel<<<NSEQ/64, 256, 0, stream>>>(sx_hi, sx_lo, Wih, Whh, bih, bhh, Wfc, bfc, out);
}

// Round 5
// 559.340 us; speedup vs baseline: 5.1022x; 1.1716x over previous
//
#include <hip/hip_runtime.h>
#include <math.h>

#define NB 64
#define NN 207
#define NT 48
#define NF 6
#define NH 64
#define NSEQ (NB*NN)          // 13248 = 207 * 64 exactly
#define TPLANE (NSEQ*NH)      // elements per t-plane in seqx [t][seq][64]

typedef short bf8_t __attribute__((ext_vector_type(8)));
typedef float f4_t  __attribute__((ext_vector_type(4)));
typedef unsigned short ushort;

__device__ __forceinline__ ushort bf16h(float x){
  unsigned int u = __float_as_uint(x);
  return (ushort)((u + 0x7FFF + ((u>>16)&1)) >> 16);
}
__device__ __forceinline__ float bf16f(ushort h){
  return __uint_as_float((unsigned int)h << 16);
}

// ---------------- GCN v2: layer1 VALU + layer2 split-bf16 MFMA ----------------
// One block per (b,t). S-terms folded: S1=(Σ_n x)@W1, S2=(Σ_n h1)@W2.
// h1 lives in LDS as bf16 hi/lo planes [208 rows][72 stride] (row 207 = zero pad);
// W2 B-fragments register-resident per wave. Epilogue restages h2 through the
// reused planes for coalesced float4 global writes.
#define HW 72                       // ushort row stride, 144 B (16B-mult, 2-way banks)
#define GCN2_LDS_BYTES (208*HW*2*2 + NN*NF*4 + NF*64*4 + 5*64*4 + 8*4)

__global__ __launch_bounds__(256, 2) void gcn_kernel(
    const float* __restrict__ x, const float* __restrict__ W1, const float* __restrict__ b1,
    const float* __restrict__ W2, const float* __restrict__ b2,
    ushort* __restrict__ sx_hi, ushort* __restrict__ sx_lo)
{
  extern __shared__ char smraw[];
  ushort* h1h = (ushort*)smraw;            // [208][72]
  ushort* h1l = h1h + 208*HW;              // [208][72]
  float*  xs  = (float*)(h1l + 208*HW);    // [207][6]
  float*  W1s = xs  + NN*NF;               // [6][64]
  float*  b1s = W1s + NF*64;
  float*  b2s = b1s + 64;
  float*  S1  = b2s + 64;
  float*  S2  = S1  + 64;
  float*  r1  = S2  + 64;
  float*  xsA = r1  + 64;                  // [6] + pad

  const int tid = threadIdx.x;
  const int t = blockIdx.x, b = blockIdx.y;
  const float inv = 1.0f/208.0f;
  const int l = tid & 63;
  const int w = __builtin_amdgcn_readfirstlane(tid >> 6);
  const int col = l & 15, q = l >> 4;
  const int cw = w*16 + col;               // this lane's output column (h2 dim)

  // ---- early: issue W2 B-fragment global loads (no LDS dependency) ----
  float wtmp[16];
  #pragma unroll
  for (int kc=0;kc<2;kc++)
    #pragma unroll
    for (int j=0;j<8;j++)
      wtmp[kc*8+j] = W2[(size_t)(kc*32 + q*8 + j)*64 + cw];

  // ---- stage ----
  for (int i=tid;i<NF*64;i+=256) W1s[i]=W1[i];
  if (tid<64){ b1s[tid]=b1[tid]; b2s[tid]=b2[tid]; S2[tid]=0.f; r1[tid]=0.f; }
  if (tid<8) xsA[tid]=0.f;
  if (tid<72){ h1h[207*HW+tid]=0; h1l[207*HW+tid]=0; }   // zero pad row
  {
    const float* xb = x + (size_t)b*NN*NT*NF + (size_t)t*NF;
    for (int i=tid;i<NN*NF;i+=256){ int n=i/NF, f=i-n*NF; xs[i] = xb[(size_t)n*NT*NF + f]; }
  }
  __syncthreads();

  // ---- xsum over n (48 threads), then S1 = xsum @ W1 ----
  if (tid < 48){
    int f = tid/8, p = tid&7;
    float ps = 0.f;
    for (int n=p; n<NN; n+=8) ps += xs[n*NF+f];
    atomicAdd(&xsA[f], ps);
  }
  __syncthreads();
  if (tid < 64){
    float a = 0.f;
    #pragma unroll
    for (int f=0;f<NF;f++) a += xsA[f]*W1s[f*64+tid];
    S1[tid] = a;
  }
  __syncthreads();

  // ---- layer 1: h1 = relu((x@W1 + S1)/208 + b1) -> bf16 hi/lo planes + r1 ----
  #pragma unroll 1
  for (int p=0;p<4;p++){
    int tile = p*256 + tid;                // 832 tiles: nt in [0,52), ht in [0,16)
    if (tile < 832){
      int nt = tile>>4, ht = tile&15;
      float colsum[4] = {0.f,0.f,0.f,0.f};
      #pragma unroll
      for (int i=0;i<4;i++){
        int n = 4*nt+i;
        if (n < NN){
          float a0=0.f,a1=0.f,a2=0.f,a3=0.f;
          #pragma unroll
          for (int f=0;f<NF;f++){
            float xv = xs[n*NF+f];
            float4 wv = *(const float4*)&W1s[f*64 + 4*ht];
            a0 += xv*wv.x; a1 += xv*wv.y; a2 += xv*wv.z; a3 += xv*wv.w;
          }
          float v0 = (a0 + S1[4*ht+0])*inv + b1s[4*ht+0]; v0 = v0>0.f?v0:0.f;
          float v1 = (a1 + S1[4*ht+1])*inv + b1s[4*ht+1]; v1 = v1>0.f?v1:0.f;
          float v2 = (a2 + S1[4*ht+2])*inv + b1s[4*ht+2]; v2 = v2>0.f?v2:0.f;
          float v3 = (a3 + S1[4*ht+3])*inv + b1s[4*ht+3]; v3 = v3>0.f?v3:0.f;
          ushort4 hi, lo;
          hi.x=bf16h(v0); lo.x=bf16h(v0-bf16f(hi.x));
          hi.y=bf16h(v1); lo.y=bf16h(v1-bf16f(hi.y));
          hi.z=bf16h(v2); lo.z=bf16h(v2-bf16f(hi.z));
          hi.w=bf16h(v3); lo.w=bf16h(v3-bf16f(hi.w));
          *(ushort4*)&h1h[n*HW + 4*ht] = hi;
          *(ushort4*)&h1l[n*HW + 4*ht] = lo;
          colsum[0]+=v0; colsum[1]+=v1; colsum[2]+=v2; colsum[3]+=v3;
        }
      }
      #pragma unroll
      for (int j=0;j<4;j++) atomicAdd(&r1[4*ht+j], colsum[j]);
    }
  }
  __syncthreads();

  // ---- S2 = r1 @ W2 (distributed over 256 threads; overlaps MFMA issue) ----
  {
    int h = tid & 63, pp = tid >> 6;
    float ps = 0.f;
    #pragma unroll
    for (int k=0;k<16;k++) ps += r1[pp*16+k]*W2[(size_t)(pp*16+k)*64 + h];
    atomicAdd(&S2[h], ps);
  }

  // ---- convert W2 B-fragments to split-bf16 ----
  bf8_t B2h[2], B2l[2];
  #pragma unroll
  for (int kc=0;kc<2;kc++){
    bf8_t ph, pl;
    #pragma unroll
    for (int j=0;j<8;j++){
      float wv = wtmp[kc*8+j];
      ushort hb = bf16h(wv);
      ph[j] = (short)hb;
      pl[j] = (short)bf16h(wv - bf16f(hb));
    }
    B2h[kc]=ph; B2l[kc]=pl;
  }

  // ---- layer 2 MFMA: Y2 tiles, wave w owns cols [16w,16w+16) ----
  f4_t acc[13];
  #pragma unroll
  for (int mt=0;mt<13;mt++){ f4_t z; z[0]=0.f;z[1]=0.f;z[2]=0.f;z[3]=0.f; acc[mt]=z; }
  #pragma unroll 2
  for (int mt=0;mt<13;mt++){
    #pragma unroll
    for (int kc=0;kc<2;kc++){
      bf8_t ah = *(const bf8_t*)(h1h + (mt*16+col)*HW + kc*32 + q*8);
      bf8_t al = *(const bf8_t*)(h1l + (mt*16+col)*HW + kc*32 + q*8);
      acc[mt] = __builtin_amdgcn_mfma_f32_16x16x32_bf16(ah, B2h[kc], acc[mt], 0,0,0);
      acc[mt] = __builtin_amdgcn_mfma_f32_16x16x32_bf16(al, B2h[kc], acc[mt], 0,0,0);
      acc[mt] = __builtin_amdgcn_mfma_f32_16x16x32_bf16(ah, B2l[kc], acc[mt], 0,0,0);
    }
  }
  __syncthreads();   // all h1 reads + S2 atomics complete

  // ---- epilogue: h2 = relu((Y2+S2)/208 + b2) -> split bf16 into reused planes ----
  {
    const float s2v = S2[cw], b2v = b2s[cw];
    #pragma unroll
    for (int mt=0;mt<13;mt++){
      #pragma unroll
      for (int r=0;r<4;r++){
        int n = mt*16 + q*4 + r;           // row 207 written but never copied out
        float v = (acc[mt][r] + s2v)*inv + b2v;
        v = v>0.f ? v : 0.f;
        ushort hb = bf16h(v);
        h1h[n*HW + cw] = hb;
        h1l[n*HW + cw] = bf16h(v - bf16f(hb));
      }
    }
  }
  __syncthreads();

  // ---- coalesced global write: [t][b*207+n][h], float4 chunks ----
  {
    const size_t obase = (size_t)t*TPLANE + (size_t)(b*NN)*NH;   // ushort elements
    for (int i=tid; i<1656; i+=256){       // 207 rows * 8 float4/row
      int n = i>>3, c = i&7;
      *(float4*)(sx_hi + obase + (size_t)n*NH + c*8) = *(const float4*)(h1h + n*HW + c*8);
      *(float4*)(sx_lo + obase + (size_t)n*NH + c*8) = *(const float4*)(h1l + n*HW + c*8);
    }
  }
}

// ---------------- LSTM v4: split-bf16 MFMA, weights register-resident ----------------
#define XW 72

__device__ __forceinline__ float fsig(float x){
  return 1.0f/(1.0f + __expf(-x));
}
__device__ __forceinline__ float ftanh(float x){
  x = fminf(15.0f, fmaxf(-15.0f, x));
  float e = __expf(2.0f*x);
  return (e - 1.0f)/(e + 1.0f);
}

__global__ __launch_bounds__(256, 1) void lstm4_kernel(
    const ushort* __restrict__ sx_hi, const ushort* __restrict__ sx_lo,
    const float* __restrict__ Wih, const float* __restrict__ Whh,
    const float* __restrict__ bih, const float* __restrict__ bhh,
    const float* __restrict__ Wfc, const float* __restrict__ bfc, float* __restrict__ out)
{
  __shared__ ushort lds[4*64*XW];      // xh, xl, hh, hl  (36864 B)
  ushort* xh = lds;
  ushort* xl = xh + 64*XW;
  ushort* hh = xl + 64*XW;
  ushort* hl = hh + 64*XW;

  const int tid = threadIdx.x;
  const int l = tid & 63;
  const int w = __builtin_amdgcn_readfirstlane(tid >> 6);
  const int col = l & 15, q = l >> 4;
  const int d0 = w*16;
  const int s0 = blockIdx.x * 64;

  bf8_t Bh[4][4], Bl[4][4];
  #pragma unroll
  for (int mat=0; mat<2; mat++){
    const float* W = mat ? Whh : Wih;
    #pragma unroll
    for (int ty=0; ty<4; ty++){
      #pragma unroll
      for (int kc2=0; kc2<2; kc2++){
        const float* wp = W + (size_t)(ty*64 + d0 + col)*64 + kc2*32 + q*8;
        bf8_t ph, pl;
        #pragma unroll
        for (int j=0;j<8;j++){
          float wv = wp[j];
          ushort hb = bf16h(wv);
          ph[j] = (short)hb;
          pl[j] = (short)bf16h(wv - bf16f(hb));
        }
        Bh[ty][mat*2+kc2] = ph;
        Bl[ty][mat*2+kc2] = pl;
      }
    }
  }

  for (int i=tid;i<2*64*XW;i+=256) hh[i]=0;
  {
    const int ss = tid>>2, ch = tid&3;
    size_t base = (size_t)(s0+ss)*64 + ch*16;
    const float4* gh = (const float4*)(sx_hi + base);
    const float4* gl = (const float4*)(sx_lo + base);
    float4 a0=gh[0], a1=gh[1], b0=gl[0], b1=gl[1];
    *(float4*)(xh + ss*XW + ch*16)     = a0;
    *(float4*)(xh + ss*XW + ch*16 + 8) = a1;
    *(float4*)(xl + ss*XW + ch*16)     = b0;
    *(float4*)(xl + ss*XW + ch*16 + 8) = b1;
  }

  float bias[4];
  #pragma unroll
  for (int ty=0;ty<4;ty++){
    int r = ty*64 + d0 + col;
    bias[ty] = bih[r] + bhh[r];
  }
  float c[16];
  #pragma unroll
  for (int i=0;i<16;i++) c[i]=0.f;

  __syncthreads();

  const int ss = tid>>2, ch = tid&3;
  const int d = d0 + col;

  for (int t=0; t<NT; t++){
    f4_t acc[4][4];
    #pragma unroll
    for (int mt=0;mt<4;mt++)
      #pragma unroll
      for (int ty=0;ty<4;ty++){
        f4_t z; z[0]=bias[ty]; z[1]=bias[ty]; z[2]=bias[ty]; z[3]=bias[ty];
        acc[mt][ty]=z;
      }

    float4 px0,px1,px2,px3;
    const bool pf = (t+1 < NT);
    if (pf){
      size_t base = (size_t)(t+1)*TPLANE + (size_t)(s0+ss)*64 + ch*16;
      const float4* gh = (const float4*)(sx_hi + base);
      const float4* gl = (const float4*)(sx_lo + base);
      px0=gh[0]; px1=gh[1]; px2=gl[0]; px3=gl[1];
    }

    #pragma unroll
    for (int kc=0;kc<4;kc++){
      const ushort* srch = (kc<2)? xh : hh;
      const ushort* srcl = (kc<2)? xl : hl;
      const int ko = (kc&1)*32 + q*8;
      bf8_t ah[4], al[4];
      #pragma unroll
      for (int mt=0;mt<4;mt++){
        ah[mt] = *(const bf8_t*)(srch + (mt*16+col)*XW + ko);
        al[mt] = *(const bf8_t*)(srcl + (mt*16+col)*XW + ko);
      }
      #pragma unroll
      for (int mt=0;mt<4;mt++){
        #pragma unroll
        for (int ty=0;ty<4;ty++){
          acc[mt][ty] = __builtin_amdgcn_mfma_f32_16x16x32_bf16(ah[mt], Bh[ty][kc], acc[mt][ty], 0,0,0);
          acc[mt][ty] = __builtin_amdgcn_mfma_f32_16x16x32_bf16(al[mt], Bh[ty][kc], acc[mt][ty], 0,0,0);
          acc[mt][ty] = __builtin_amdgcn_mfma_f32_16x16x32_bf16(ah[mt], Bl[ty][kc], acc[mt][ty], 0,0,0);
        }
      }
    }
    __syncthreads();

    if (pf){
      *(float4*)(xh + ss*XW + ch*16)     = px0;
      *(float4*)(xh + ss*XW + ch*16 + 8) = px1;
      *(float4*)(xl + ss*XW + ch*16)     = px2;
      *(float4*)(xl + ss*XW + ch*16 + 8) = px3;
    }

    #pragma unroll
    for (int mt=0;mt<4;mt++){
      #pragma unroll
      for (int r=0;r<4;r++){
        const int s = mt*16 + q*4 + r;
        float gi = acc[mt][0][r], gf = acc[mt][1][r], gg = acc[mt][2][r], go = acc[mt][3][r];
        float ig = fsig(gi), fg = fsig(gf), gt = ftanh(gg), og = fsig(go);
        float cc = fg*c[mt*4+r] + ig*gt;
        c[mt*4+r] = cc;
        float hv = og*ftanh(cc);
        if (t != NT-1){
          ushort hb = bf16h(hv);
          hh[s*XW + d] = hb;
          hl[s*XW + d] = bf16h(hv - bf16f(hb));
        } else {
          ((float*)lds)[s*68 + d] = hv;
        }
      }
    }
    __syncthreads();
  }

  if (tid < 64){
    const float* hf = (const float*)lds;
    float a = bfc[0];
    #pragma unroll 8
    for (int k=0;k<64;k++) a += hf[tid*68+k]*Wfc[k];
    out[s0+tid] = a;
  }
}

extern "C" void kernel_launch(void* const* d_in, const int* in_sizes, int n_in,
                              void* d_out, int out_size, void* d_ws, size_t ws_size,
                              hipStream_t stream) {
  const float* x   = (const float*)d_in[0];
  // d_in[1], d_in[2] (N1, N2): structurally dead — sigmoid(N1@N2)>0 is all-ones.
  const float* W1  = (const float*)d_in[3];
  const float* b1  = (const float*)d_in[4];
  const float* W2  = (const float*)d_in[5];
  const float* b2  = (const float*)d_in[6];
  const float* Wih = (const float*)d_in[7];
  const float* Whh = (const float*)d_in[8];
  const float* bih = (const float*)d_in[9];
  const float* bhh = (const float*)d_in[10];
  const float* Wfc = (const float*)d_in[11];
  const float* bfc = (const float*)d_in[12];

  ushort* sx_hi = (ushort*)d_ws;                         // [48][13248][64] bf16 hi
  ushort* sx_lo = sx_hi + (size_t)NT*TPLANE;             // [48][13248][64] bf16 lo
  float*  out   = (float*)d_out;

  hipFuncSetAttribute((const void*)gcn_kernel, hipFuncAttributeMaxDynamicSharedMemorySize, GCN2_LDS_BYTES);

  gcn_kernel<<<dim3(NT, NB), 256, GCN2_LDS_BYTES, stream>>>(x, W1, b1, W2, b2, sx_hi, sx_lo);
  lstm4_kernel<<<NSEQ/64, 256, 0, stream>>>(sx_hi, sx_lo, Wih, Whh, bih, bhh, Wfc, bfc, out);
}

// Round 6
// 505.638 us; speedup vs baseline: 5.6441x; 1.1062x over previous
//
#include <hip/hip_runtime.h>
#include <math.h>

#define NB 64
#define NN 207
#define NT 48
#define NF 6
#define NH 64
#define NSEQ (NB*NN)        // 13248 = 207*64
#define NSB  (NSEQ/64)      // 207 LSTM blocks of 64 seqs
#define FRAG 4096           // ushorts per (t,sb) fragment plane: [4 mt][2 kc][64 chunk][8]

typedef short bf8_t __attribute__((ext_vector_type(8)));
typedef float f4_t  __attribute__((ext_vector_type(4)));
typedef unsigned short ushort;

__device__ __forceinline__ ushort bf16h(float x){
  unsigned int u = __float_as_uint(x);
  return (ushort)((u + 0x7FFF + ((u>>16)&1)) >> 16);
}
__device__ __forceinline__ float bf16f(ushort h){
  return __uint_as_float((unsigned int)h << 16);
}
__device__ __forceinline__ float fsig(float x){ return 1.0f/(1.0f + __expf(-x)); }
__device__ __forceinline__ float ftanh(float x){
  x = fminf(15.0f, fmaxf(-15.0f, x));
  float e = __expf(2.0f*x);
  return (e - 1.0f)/(e + 1.0f);
}

// Fragment-order addressing for a 64-seq x 64-dim bf16 plane (MFMA A-operand):
// element (s in [0,64), k in [0,64)) -> (s>>4)*1024 + (k>>5)*512 + ((s&15)*4 + ((k>>3)&3))*8 + (k&7)

// ---------------- GCN v3: layer1 VALU + layer2 single-bf16 MFMA ----------------
// One block per (b,t), 4 blocks/CU. h1 single bf16 plane (the /208 in layer2
// makes bf16 inputs error-free to ~5e-7); 3 barriers; epilogue writes split-bf16
// h2 directly to global in LSTM fragment order (no LDS restage).
#define HW 72
#define GCN3_LDS_BYTES (208*HW*2 + (NN*NF + NF*64 + 64 + 64 + 64 + 64 + 8)*4)

__global__ __launch_bounds__(256, 4) void gcn_kernel(
    const float* __restrict__ x, const float* __restrict__ W1, const float* __restrict__ b1,
    const float* __restrict__ W2, const float* __restrict__ b2,
    ushort* __restrict__ sxh, ushort* __restrict__ sxl)
{
  extern __shared__ char smraw[];
  ushort* h1b = (ushort*)smraw;            // [208][72] bf16 (row 207 = zero pad)
  float*  xs  = (float*)(h1b + 208*HW);    // [207][6]
  float*  W1s = xs + NN*NF;                // [6][64]
  float*  b1s = W1s + NF*64;               // 64
  float*  b2s = b1s + 64;                  // 64
  float*  S2  = b2s + 64;                  // 64
  float*  r1  = S2 + 64;                   // 64
  float*  xsA = r1 + 64;                   // 8

  const int tid = threadIdx.x;
  const int t = blockIdx.x, b = blockIdx.y;
  const float inv = 1.0f/208.0f;
  const int l = tid & 63;
  const int w = __builtin_amdgcn_readfirstlane(tid >> 6);
  const int col = l & 15, q = l >> 4;
  const int cw = w*16 + col;               // this lane's h2 output dim

  if (tid < 64){ S2[tid]=0.f; r1[tid]=0.f; }
  if (tid < 8) xsA[tid]=0.f;
  if (tid < 72) h1b[207*HW + tid] = 0;
  __syncthreads();

  // stage xs (+ xsum atomics), W1s, biases
  for (int i=tid;i<NF*64;i+=256) W1s[i]=W1[i];
  if (tid<64){ b1s[tid]=b1[tid]; b2s[tid]=b2[tid]; }
  {
    const float* xb = x + (size_t)b*NN*NT*NF + (size_t)t*NF;
    for (int i=tid;i<NN*NF;i+=256){
      int n=i/NF, f=i-n*NF;
      float v = xb[(size_t)n*NT*NF + f];
      xs[i] = v;
      atomicAdd(&xsA[f], v);
    }
  }
  __syncthreads();

  // W2 fragment loads: issued here, consumed after layer1 (latency hidden)
  float wtmp[16];
  #pragma unroll
  for (int kc=0;kc<2;kc++)
    #pragma unroll
    for (int j=0;j<8;j++)
      wtmp[kc*8+j] = W2[(size_t)(kc*32 + q*8 + j)*64 + cw];

  // ---- layer 1: h1 = relu((x@W1 + S1)/208 + b1), S1 computed locally ----
  #pragma unroll 1
  for (int p=0;p<4;p++){
    int tile = p*256 + tid;                // 832 tiles: nt in [0,52), ht in [0,16)
    if (tile < 832){
      int nt = tile>>4, ht = tile&15;
      float s1v[4];
      #pragma unroll
      for (int j=0;j<4;j++){
        float a = 0.f;
        #pragma unroll
        for (int f=0;f<NF;f++) a += xsA[f]*W1s[f*64 + 4*ht + j];
        s1v[j] = a;
      }
      float cs0=0.f, cs1=0.f, cs2=0.f, cs3=0.f;
      #pragma unroll
      for (int i=0;i<4;i++){
        int n = 4*nt+i;
        if (n < NN){
          float a0=0.f,a1=0.f,a2=0.f,a3=0.f;
          #pragma unroll
          for (int f=0;f<NF;f++){
            float xv = xs[n*NF+f];
            float4 wv = *(const float4*)&W1s[f*64 + 4*ht];
            a0+=xv*wv.x; a1+=xv*wv.y; a2+=xv*wv.z; a3+=xv*wv.w;
          }
          float v0=(a0+s1v[0])*inv + b1s[4*ht+0]; v0 = v0>0.f?v0:0.f;
          float v1=(a1+s1v[1])*inv + b1s[4*ht+1]; v1 = v1>0.f?v1:0.f;
          float v2=(a2+s1v[2])*inv + b1s[4*ht+2]; v2 = v2>0.f?v2:0.f;
          float v3=(a3+s1v[3])*inv + b1s[4*ht+3]; v3 = v3>0.f?v3:0.f;
          ushort4 hi;
          hi.x=bf16h(v0); hi.y=bf16h(v1); hi.z=bf16h(v2); hi.w=bf16h(v3);
          *(ushort4*)&h1b[n*HW + 4*ht] = hi;
          cs0+=v0; cs1+=v1; cs2+=v2; cs3+=v3;
        }
      }
      atomicAdd(&r1[4*ht+0], cs0);
      atomicAdd(&r1[4*ht+1], cs1);
      atomicAdd(&r1[4*ht+2], cs2);
      atomicAdd(&r1[4*ht+3], cs3);
    }
  }
  __syncthreads();

  // ---- S2 = r1 @ W2 (fp32, exact) ----
  {
    int h = tid & 63, pp = tid >> 6;
    float ps = 0.f;
    #pragma unroll
    for (int k=0;k<16;k++) ps += r1[pp*16+k]*W2[(size_t)(pp*16+k)*64 + h];
    atomicAdd(&S2[h], ps);
  }

  // ---- layer 2: single-bf16 MFMA ----
  bf8_t B2[2];
  #pragma unroll
  for (int kc=0;kc<2;kc++){
    bf8_t ph;
    #pragma unroll
    for (int j=0;j<8;j++) ph[j] = (short)bf16h(wtmp[kc*8+j]);
    B2[kc]=ph;
  }
  f4_t acc[13];
  #pragma unroll
  for (int mt=0;mt<13;mt++){ f4_t z; z[0]=0.f;z[1]=0.f;z[2]=0.f;z[3]=0.f; acc[mt]=z; }
  #pragma unroll 2
  for (int mt=0;mt<13;mt++){
    #pragma unroll
    for (int kc=0;kc<2;kc++){
      bf8_t ah = *(const bf8_t*)(h1b + (mt*16+col)*HW + kc*32 + q*8);
      acc[mt] = __builtin_amdgcn_mfma_f32_16x16x32_bf16(ah, B2[kc], acc[mt], 0,0,0);
    }
  }
  __syncthreads();   // S2 atomics + all h1 reads complete

  // ---- epilogue: h2 split-bf16 -> global, LSTM fragment order ----
  {
    const float s2v = S2[cw], b2v = b2s[cw];
    const int ccw = ((cw>>5)<<9) + (((cw>>3)&3)<<3) + (cw&7);
    #pragma unroll
    for (int mt=0;mt<13;mt++){
      #pragma unroll
      for (int r=0;r<4;r++){
        int n = mt*16 + q*4 + r;
        if (n < NN){
          float v = (acc[mt][r] + s2v)*inv + b2v;
          v = v>0.f ? v : 0.f;
          ushort hb = bf16h(v);
          ushort lb = bf16h(v - bf16f(hb));
          int sg = b*NN + n;
          size_t addr = ((size_t)t*NSB + (size_t)(sg>>6))*FRAG
                      + (size_t)(((sg&63)>>4)*1024 + ((sg&15)<<5) + ccw);
          sxh[addr] = hb;
          sxl[addr] = lb;
        }
      }
    }
  }
}

// ---------------- LSTM v5: 8 waves, 1 barrier/step, x direct from global ----------------
// 207 blocks x 512 threads. Wave (wm = w>>2, wn = w&3): wm picks seqs [32wm,32wm+32)
// (mt = 2wm, 2wm+1), wn picks gate dims [16wn,16wn+16) x 4 types. B-fragments
// (hi+lo, 128 VGPRs) register-resident. h double-buffered in LDS fragment order
// (conflict-free b128); x fragments prefetched one step ahead global->VGPR.
__global__ __launch_bounds__(512, 2) void lstm5_kernel(
    const ushort* __restrict__ sxh, const ushort* __restrict__ sxl,
    const float* __restrict__ Wih, const float* __restrict__ Whh,
    const float* __restrict__ bih, const float* __restrict__ bhh,
    const float* __restrict__ Wfc, const float* __restrict__ bfc, float* __restrict__ out)
{
  __shared__ ushort hpl[2][2][FRAG];   // [buf][hi/lo][frag] = 32 KB
  const int tid = threadIdx.x;
  const int l = tid & 63;
  const int w = __builtin_amdgcn_readfirstlane(tid >> 6);
  const int wn = w & 3, wm = w >> 2;
  const int col = l & 15, q = l >> 4;
  const int sb = blockIdx.x;

  // ---- B fragments: [ty][kc], kc 0,1 = x (Wih), 2,3 = h (Whh) ----
  bf8_t Bh[4][4], Bl[4][4];
  #pragma unroll
  for (int mat=0; mat<2; mat++){
    const float* W = mat ? Whh : Wih;
    #pragma unroll
    for (int ty=0; ty<4; ty++){
      #pragma unroll
      for (int kk=0; kk<2; kk++){
        const float* wp = W + (size_t)(ty*64 + wn*16 + col)*64 + kk*32 + q*8;
        bf8_t ph, pl;
        #pragma unroll
        for (int j=0;j<8;j++){
          float wv = wp[j];
          ushort hb = bf16h(wv);
          ph[j] = (short)hb;
          pl[j] = (short)bf16h(wv - bf16f(hb));
        }
        Bh[ty][mat*2+kk] = ph;
        Bl[ty][mat*2+kk] = pl;
      }
    }
  }
  float bias[4];
  #pragma unroll
  for (int ty=0;ty<4;ty++){
    int r = ty*64 + wn*16 + col;
    bias[ty] = bih[r] + bhh[r];
  }
  float c[8];
  #pragma unroll
  for (int i=0;i<8;i++) c[i]=0.f;

  // zero h buffer 0 (16 KB)
  {
    uint4 z = {0,0,0,0};
    for (int i=tid; i<1024; i+=512) ((uint4*)hpl)[i] = z;
  }

  const int fo = (col*4 + q)*8;                    // read-chunk offset within a frag
  const int m0 = wm*2;                              // first owned global m-tile
  const int dw = wn*16 + col;                       // owned h-dim
  const int Cw = ((dw>>5)<<9) + (((dw>>3)&3)<<3) + (dw&7);  // h-write const

  // x(0) prefetch
  bf8_t xAh[2][2], xAl[2][2], xBh[2][2], xBl[2][2];
  {
    const size_t xb0 = (size_t)sb*FRAG;
    #pragma unroll
    for (int m=0;m<2;m++)
      #pragma unroll
      for (int kk=0;kk<2;kk++){
        size_t off = xb0 + (size_t)((m0+m)*1024 + kk*512 + fo);
        xAh[m][kk] = *(const bf8_t*)(sxh + off);
        xAl[m][kk] = *(const bf8_t*)(sxl + off);
      }
  }
  __syncthreads();

#define LSTEP(T, XH, XL, NXH, NXL) { \
    const int cur = (T)&1; \
    if ((T)+1 < NT){ \
      const size_t xb = ((size_t)((T)+1)*NSB + sb)*FRAG; \
      _Pragma("unroll") \
      for (int m=0;m<2;m++){ \
        _Pragma("unroll") \
        for (int kk=0;kk<2;kk++){ \
          size_t off = xb + (size_t)((m0+m)*1024 + kk*512 + fo); \
          NXH[m][kk] = *(const bf8_t*)(sxh + off); \
          NXL[m][kk] = *(const bf8_t*)(sxl + off); \
        } \
      } \
    } \
    f4_t acc[2][4]; \
    _Pragma("unroll") \
    for (int m=0;m<2;m++){ \
      _Pragma("unroll") \
      for (int ty=0;ty<4;ty++){ f4_t z; z[0]=bias[ty];z[1]=bias[ty];z[2]=bias[ty];z[3]=bias[ty]; acc[m][ty]=z; } \
    } \
    bf8_t hh_[2][2], hl_[2][2]; \
    _Pragma("unroll") \
    for (int m=0;m<2;m++){ \
      _Pragma("unroll") \
      for (int kk=0;kk<2;kk++){ \
        const ushort* hp0 = &hpl[cur][0][(m0+m)*1024 + kk*512 + fo]; \
        hh_[m][kk] = *(const bf8_t*)hp0; \
        hl_[m][kk] = *(const bf8_t*)(hp0 + FRAG); \
      } \
    } \
    _Pragma("unroll") \
    for (int kk=0;kk<2;kk++){ \
      _Pragma("unroll") \
      for (int m=0;m<2;m++){ \
        _Pragma("unroll") \
        for (int ty=0;ty<4;ty++){ \
          acc[m][ty] = __builtin_amdgcn_mfma_f32_16x16x32_bf16(XH[m][kk], Bh[ty][kk], acc[m][ty], 0,0,0); \
          acc[m][ty] = __builtin_amdgcn_mfma_f32_16x16x32_bf16(XL[m][kk], Bh[ty][kk], acc[m][ty], 0,0,0); \
          acc[m][ty] = __builtin_amdgcn_mfma_f32_16x16x32_bf16(XH[m][kk], Bl[ty][kk], acc[m][ty], 0,0,0); \
        } \
      } \
    } \
    _Pragma("unroll") \
    for (int kk=0;kk<2;kk++){ \
      _Pragma("unroll") \
      for (int m=0;m<2;m++){ \
        _Pragma("unroll") \
        for (int ty=0;ty<4;ty++){ \
          acc[m][ty] = __builtin_amdgcn_mfma_f32_16x16x32_bf16(hh_[m][kk], Bh[ty][2+kk], acc[m][ty], 0,0,0); \
          acc[m][ty] = __builtin_amdgcn_mfma_f32_16x16x32_bf16(hl_[m][kk], Bh[ty][2+kk], acc[m][ty], 0,0,0); \
          acc[m][ty] = __builtin_amdgcn_mfma_f32_16x16x32_bf16(hh_[m][kk], Bl[ty][2+kk], acc[m][ty], 0,0,0); \
        } \
      } \
    } \
    _Pragma("unroll") \
    for (int m=0;m<2;m++){ \
      _Pragma("unroll") \
      for (int r=0;r<4;r++){ \
        float gi=acc[m][0][r], gf=acc[m][1][r], gg=acc[m][2][r], go=acc[m][3][r]; \
        float ig=fsig(gi), fg=fsig(gf), gt=ftanh(gg), og=fsig(go); \
        float cc = fg*c[m*4+r] + ig*gt; \
        c[m*4+r] = cc; \
        float hv = og*ftanh(cc); \
        if ((T) != NT-1){ \
          ushort hb2 = bf16h(hv); \
          int woff = (m0+m)*1024 + Cw + ((q*4+r)<<5); \
          hpl[cur^1][0][woff] = hb2; \
          hpl[cur^1][1][woff] = bf16h(hv - bf16f(hb2)); \
        } else { \
          ((float*)hpl)[dw*64 + (m0+m)*16 + q*4 + r] = hv; \
        } \
      } \
    } \
    __syncthreads(); \
  }

  #pragma unroll 1
  for (int tt=0; tt<NT; tt+=2){
    LSTEP(tt,   xAh, xAl, xBh, xBl)
    LSTEP(tt+1, xBh, xBl, xAh, xAl)
  }
#undef LSTEP

  // epilogue: out[seq] = h_T . W_fc + b_fc  (h_T fp32 transposed in hpl[0] region)
  if (tid < 64){
    float a = bfc[0];
    const float* hf = (const float*)hpl;
    #pragma unroll 8
    for (int k=0;k<64;k++) a += hf[k*64 + tid]*Wfc[k];
    out[sb*64 + tid] = a;
  }
}

extern "C" void kernel_launch(void* const* d_in, const int* in_sizes, int n_in,
                              void* d_out, int out_size, void* d_ws, size_t ws_size,
                              hipStream_t stream) {
  const float* x   = (const float*)d_in[0];
  // d_in[1], d_in[2] (N1, N2): structurally dead — sigmoid(N1@N2)>0 is all-ones.
  const float* W1  = (const float*)d_in[3];
  const float* b1  = (const float*)d_in[4];
  const float* W2  = (const float*)d_in[5];
  const float* b2  = (const float*)d_in[6];
  const float* Wih = (const float*)d_in[7];
  const float* Whh = (const float*)d_in[8];
  const float* bih = (const float*)d_in[9];
  const float* bhh = (const float*)d_in[10];
  const float* Wfc = (const float*)d_in[11];
  const float* bfc = (const float*)d_in[12];

  ushort* sxh = (ushort*)d_ws;                       // [48][207 sb][4096] bf16 hi (81.4 MB)
  ushort* sxl = sxh + (size_t)NT*NSB*FRAG;           // same, lo (81.4 MB)
  float*  out = (float*)d_out;

  hipFuncSetAttribute((const void*)gcn_kernel, hipFuncAttributeMaxDynamicSharedMemorySize, GCN3_LDS_BYTES);

  gcn_kernel<<<dim3(NT, NB), 256, GCN3_LDS_BYTES, stream>>>(x, W1, b1, W2, b2, sxh, sxl);
  lstm5_kernel<<<NSB, 512, 0, stream>>>(sxh, sxl, Wih, Whh, bih, bhh, Wfc, bfc, out);
}

// Round 7
// 418.760 us; speedup vs baseline: 6.8150x; 1.2075x over previous
//
#include <hip/hip_runtime.h>
#include <math.h>

#define NB 64
#define NN 207
#define NT 48
#define NF 6
#define NH 64
#define NSEQ (NB*NN)        // 13248 = 828*16
#define SB16 (NSEQ/16)      // 828 LSTM blocks of 16 seqs

typedef short bf8_t __attribute__((ext_vector_type(8)));
typedef float f4_t  __attribute__((ext_vector_type(4)));
typedef unsigned short ushort;
typedef unsigned int uint;

__device__ __forceinline__ ushort bf16h(float x){
  uint u = __float_as_uint(x);
  return (ushort)((u + 0x7FFF + ((u>>16)&1)) >> 16);
}
__device__ __forceinline__ float bf16f(ushort h){
  return __uint_as_float((uint)h << 16);
}
__device__ __forceinline__ float fsig(float x){
  return __builtin_amdgcn_rcpf(1.0f + __expf(-x));
}
__device__ __forceinline__ float ftanh(float x){
  x = fminf(15.0f, fmaxf(-15.0f, x));
  float e = __expf(2.0f*x);
  return 1.0f - 2.0f*__builtin_amdgcn_rcpf(e + 1.0f);
}

// interchange: sxp[t][sg][64] u32, each = (bf16_hi<<16)|bf16_lo of h2

// ---------------- GCN v4: layer1 VALU + layer2 bf16 MFMA, packed u32 rows out ----------------
#define HW 72
#define GCN4_LDS_BYTES (208*HW*2 + (NN*NF + NF*64 + 64 + 64 + 64 + 64 + 8)*4)

__global__ __launch_bounds__(256, 4) void gcn_kernel(
    const float* __restrict__ x, const float* __restrict__ W1, const float* __restrict__ b1,
    const float* __restrict__ W2, const float* __restrict__ b2, uint* __restrict__ sxp)
{
  extern __shared__ char smraw[];
  ushort* h1b = (ushort*)smraw;            // [208][72] bf16 (row 207 = zero pad)
  float*  xs  = (float*)(h1b + 208*HW);    // [207][6]
  float*  W1s = xs + NN*NF;                // [6][64]
  float*  b1s = W1s + NF*64;
  float*  b2s = b1s + 64;
  float*  S2  = b2s + 64;
  float*  r1  = S2 + 64;
  float*  xsA = r1 + 64;

  const int tid = threadIdx.x;
  const int t = blockIdx.x, b = blockIdx.y;
  const float inv = 1.0f/208.0f;
  const int l = tid & 63;
  const int w = __builtin_amdgcn_readfirstlane(tid >> 6);
  const int col = l & 15, q = l >> 4;
  const int cw = w*16 + col;

  if (tid < 64){ S2[tid]=0.f; r1[tid]=0.f; }
  if (tid < 8) xsA[tid]=0.f;
  if (tid < 72) h1b[207*HW + tid] = 0;
  __syncthreads();

  for (int i=tid;i<NF*64;i+=256) W1s[i]=W1[i];
  if (tid<64){ b1s[tid]=b1[tid]; b2s[tid]=b2[tid]; }
  {
    const float* xb = x + (size_t)b*NN*NT*NF + (size_t)t*NF;
    for (int i=tid;i<NN*NF;i+=256){
      int n=i/NF, f=i-n*NF;
      float v = xb[(size_t)n*NT*NF + f];
      xs[i] = v;
      atomicAdd(&xsA[f], v);
    }
  }
  __syncthreads();

  // W2 fragment loads (consumed after layer1; latency hidden)
  float wtmp[16];
  #pragma unroll
  for (int kc=0;kc<2;kc++)
    #pragma unroll
    for (int j=0;j<8;j++)
      wtmp[kc*8+j] = W2[(size_t)(kc*32 + q*8 + j)*64 + cw];

  // layer 1: h1 = relu((x@W1 + S1)/208 + b1) -> bf16 plane + r1
  #pragma unroll 1
  for (int p=0;p<4;p++){
    int tile = p*256 + tid;
    if (tile < 832){
      int nt = tile>>4, ht = tile&15;
      float s1v[4];
      #pragma unroll
      for (int j=0;j<4;j++){
        float a = 0.f;
        #pragma unroll
        for (int f=0;f<NF;f++) a += xsA[f]*W1s[f*64 + 4*ht + j];
        s1v[j] = a;
      }
      float cs0=0.f, cs1=0.f, cs2=0.f, cs3=0.f;
      #pragma unroll
      for (int i=0;i<4;i++){
        int n = 4*nt+i;
        if (n < NN){
          float a0=0.f,a1=0.f,a2=0.f,a3=0.f;
          #pragma unroll
          for (int f=0;f<NF;f++){
            float xv = xs[n*NF+f];
            float4 wv = *(const float4*)&W1s[f*64 + 4*ht];
            a0+=xv*wv.x; a1+=xv*wv.y; a2+=xv*wv.z; a3+=xv*wv.w;
          }
          float v0=(a0+s1v[0])*inv + b1s[4*ht+0]; v0 = v0>0.f?v0:0.f;
          float v1=(a1+s1v[1])*inv + b1s[4*ht+1]; v1 = v1>0.f?v1:0.f;
          float v2=(a2+s1v[2])*inv + b1s[4*ht+2]; v2 = v2>0.f?v2:0.f;
          float v3=(a3+s1v[3])*inv + b1s[4*ht+3]; v3 = v3>0.f?v3:0.f;
          ushort4 hi;
          hi.x=bf16h(v0); hi.y=bf16h(v1); hi.z=bf16h(v2); hi.w=bf16h(v3);
          *(ushort4*)&h1b[n*HW + 4*ht] = hi;
          cs0+=v0; cs1+=v1; cs2+=v2; cs3+=v3;
        }
      }
      atomicAdd(&r1[4*ht+0], cs0);
      atomicAdd(&r1[4*ht+1], cs1);
      atomicAdd(&r1[4*ht+2], cs2);
      atomicAdd(&r1[4*ht+3], cs3);
    }
  }
  __syncthreads();

  // S2 = r1 @ W2 (fp32 exact)
  {
    int h = tid & 63, pp = tid >> 6;
    float ps = 0.f;
    #pragma unroll
    for (int k=0;k<16;k++) ps += r1[pp*16+k]*W2[(size_t)(pp*16+k)*64 + h];
    atomicAdd(&S2[h], ps);
  }

  // layer 2: single-bf16 MFMA
  bf8_t B2[2];
  #pragma unroll
  for (int kc=0;kc<2;kc++){
    bf8_t ph;
    #pragma unroll
    for (int j=0;j<8;j++) ph[j] = (short)bf16h(wtmp[kc*8+j]);
    B2[kc]=ph;
  }
  f4_t acc[13];
  #pragma unroll
  for (int mt=0;mt<13;mt++){ f4_t z; z[0]=0.f;z[1]=0.f;z[2]=0.f;z[3]=0.f; acc[mt]=z; }
  #pragma unroll 2
  for (int mt=0;mt<13;mt++){
    #pragma unroll
    for (int kc=0;kc<2;kc++){
      bf8_t ah = *(const bf8_t*)(h1b + (mt*16+col)*HW + kc*32 + q*8);
      acc[mt] = __builtin_amdgcn_mfma_f32_16x16x32_bf16(ah, B2[kc], acc[mt], 0,0,0);
    }
  }
  __syncthreads();   // S2 atomics + all h1 reads complete

  // epilogue: h2 -> packed u32 rows [t][b*207+n][cw]
  {
    const float s2v = S2[cw], b2v = b2s[cw];
    uint* obase = sxp + ((size_t)t*NSEQ + (size_t)b*NN)*NH + cw;
    #pragma unroll
    for (int mt=0;mt<13;mt++){
      #pragma unroll
      for (int r=0;r<4;r++){
        int n = mt*16 + q*4 + r;
        if (n < NN){
          float v = (acc[mt][r] + s2v)*inv + b2v;
          v = v>0.f ? v : 0.f;
          ushort hb = bf16h(v);
          ushort lb = bf16h(v - bf16f(hb));
          obase[(size_t)n*NH] = ((uint)hb<<16) | (uint)lb;
        }
      }
    }
  }
}

// ---------------- LSTM v6: 828 blocks x 16 seqs, frag-order LDS, rcp-cheap update ----------------
// Wave w owns gate dims [16w,16w+16) x 4 types for the single 16-seq m-tile.
// B-frags (hi+lo, 128 VGPR) register-resident; x/h in LDS frag-order planes
// (b128 reads conflict-free), both double-buffered; 1 barrier/step.
__global__ __launch_bounds__(256, 2) void lstm6_kernel(
    const uint* __restrict__ sxp,
    const float* __restrict__ Wih, const float* __restrict__ Whh,
    const float* __restrict__ bih, const float* __restrict__ bhh,
    const float* __restrict__ Wfc, const float* __restrict__ bfc, float* __restrict__ out)
{
  __shared__ ushort xf[2][2][1024];   // [buf][hi/lo][frag(s,k)] 4 KB
  __shared__ ushort hf[2][2][1024];   // 4 KB

  const int tid = threadIdx.x;
  const int l = tid & 63;
  const int w = __builtin_amdgcn_readfirstlane(tid >> 6);
  const int col = l & 15, q = l >> 4;
  const int s0 = blockIdx.x * 16;

  // B fragments: [ty][mat*2+kk]; mats: 0 = Wih (x), 1 = Whh (h)
  bf8_t Bh[4][4], Bl[4][4];
  #pragma unroll
  for (int mat=0; mat<2; mat++){
    const float* W = mat ? Whh : Wih;
    #pragma unroll
    for (int ty=0; ty<4; ty++){
      #pragma unroll
      for (int kk=0; kk<2; kk++){
        const float* wp = W + (size_t)(ty*64 + w*16 + col)*64 + kk*32 + q*8;
        bf8_t ph, pl;
        #pragma unroll
        for (int j=0;j<8;j++){
          float wv = wp[j];
          ushort hb = bf16h(wv);
          ph[j] = (short)hb;
          pl[j] = (short)bf16h(wv - bf16f(hb));
        }
        Bh[ty][mat*2+kk] = ph;
        Bl[ty][mat*2+kk] = pl;
      }
    }
  }
  float bias[4];
  #pragma unroll
  for (int ty=0;ty<4;ty++){
    int r = ty*64 + w*16 + col;
    bias[ty] = bih[r] + bhh[r];
  }
  float c[4];
  #pragma unroll
  for (int i=0;i<4;i++) c[i]=0.f;

  // zero h buffer 0 (4 KB)
  for (int i=tid; i<1024; i+=256) ((uint*)hf)[i] = 0;

  // x-staging role: thread -> (seq = tid>>4, j4 = tid&15) = 4 dims
  const int ss = tid >> 4, j4 = tid & 15;
  const int k0 = j4*4;
  const int xoff = ((k0>>5)<<9) + ((ss*4 + ((k0>>3)&3))<<3) + (k0&4);  // frag offset of 4-run
  const uint* xsrc = sxp + ((size_t)s0 + ss)*NH + k0;

  // stage x(0)
  {
    uint4 p = *(const uint4*)xsrc;
    ushort4 hi, lo;
    hi.x=(ushort)(p.x>>16); lo.x=(ushort)(p.x&0xffff);
    hi.y=(ushort)(p.y>>16); lo.y=(ushort)(p.y&0xffff);
    hi.z=(ushort)(p.z>>16); lo.z=(ushort)(p.z&0xffff);
    hi.w=(ushort)(p.w>>16); lo.w=(ushort)(p.w&0xffff);
    *(ushort4*)&xf[0][0][xoff] = hi;
    *(ushort4*)&xf[0][1][xoff] = lo;
  }

  const int fo = (col*4 + q)*8;        // A-frag read offset (b128, conflict-free)
  const int d = w*16 + col;
  const int hbase = ((d>>5)<<9) + (((d>>3)&3)<<3) + (d&7) + q*128;  // + r*32
  __syncthreads();

  #pragma unroll 1
  for (int t=0; t<NT; t++){
    const int cur = t & 1;
    // prefetch x(t+1) packed (consumed post-barrier)
    uint4 px;
    const bool pf = (t+1 < NT);
    if (pf) px = *(const uint4*)(xsrc + (size_t)(t+1)*NSEQ*NH);

    f4_t acc[4];
    #pragma unroll
    for (int ty=0;ty<4;ty++){ f4_t z; z[0]=bias[ty];z[1]=bias[ty];z[2]=bias[ty];z[3]=bias[ty]; acc[ty]=z; }

    bf8_t xa_h[2], xa_l[2], ha_h[2], ha_l[2];
    #pragma unroll
    for (int kk=0;kk<2;kk++){
      xa_h[kk] = *(const bf8_t*)&xf[cur][0][kk*512 + fo];
      xa_l[kk] = *(const bf8_t*)&xf[cur][1][kk*512 + fo];
      ha_h[kk] = *(const bf8_t*)&hf[cur][0][kk*512 + fo];
      ha_l[kk] = *(const bf8_t*)&hf[cur][1][kk*512 + fo];
    }
    #pragma unroll
    for (int kk=0;kk<2;kk++){
      #pragma unroll
      for (int ty=0;ty<4;ty++){
        acc[ty] = __builtin_amdgcn_mfma_f32_16x16x32_bf16(xa_h[kk], Bh[ty][kk], acc[ty], 0,0,0);
        acc[ty] = __builtin_amdgcn_mfma_f32_16x16x32_bf16(xa_l[kk], Bh[ty][kk], acc[ty], 0,0,0);
        acc[ty] = __builtin_amdgcn_mfma_f32_16x16x32_bf16(xa_h[kk], Bl[ty][kk], acc[ty], 0,0,0);
        acc[ty] = __builtin_amdgcn_mfma_f32_16x16x32_bf16(ha_h[kk], Bh[ty][2+kk], acc[ty], 0,0,0);
        acc[ty] = __builtin_amdgcn_mfma_f32_16x16x32_bf16(ha_l[kk], Bh[ty][2+kk], acc[ty], 0,0,0);
        acc[ty] = __builtin_amdgcn_mfma_f32_16x16x32_bf16(ha_h[kk], Bl[ty][2+kk], acc[ty], 0,0,0);
      }
    }

    // update (i,f,g,o in-lane; C row = q*4+r = seq, col = gate dim)
    #pragma unroll
    for (int r=0;r<4;r++){
      float ig = fsig(acc[0][r]);
      float fg = fsig(acc[1][r]);
      float gt = ftanh(acc[2][r]);
      float og = fsig(acc[3][r]);
      float cc = fg*c[r] + ig*gt;
      c[r] = cc;
      float hv = og*ftanh(cc);
      if (t != NT-1){
        ushort hb2 = bf16h(hv);
        int off = hbase + r*32;
        hf[cur^1][0][off] = hb2;
        hf[cur^1][1][off] = bf16h(hv - bf16f(hb2));
      } else {
        ((float*)xf)[(q*4+r)*64 + d] = hv;   // final h fp32 (xf dead)
      }
    }
    // stage x(t+1) into the other buffer
    if (pf){
      ushort4 hi, lo;
      hi.x=(ushort)(px.x>>16); lo.x=(ushort)(px.x&0xffff);
      hi.y=(ushort)(px.y>>16); lo.y=(ushort)(px.y&0xffff);
      hi.z=(ushort)(px.z>>16); lo.z=(ushort)(px.z&0xffff);
      hi.w=(ushort)(px.w>>16); lo.w=(ushort)(px.w&0xffff);
      *(ushort4*)&xf[cur^1][0][xoff] = hi;
      *(ushort4*)&xf[cur^1][1][xoff] = lo;
    }
    __syncthreads();
  }

  // epilogue: out[seq] = h_T . W_fc + b_fc
  if (tid < 16){
    const float* hT = (const float*)xf;
    float a = bfc[0];
    #pragma unroll 8
    for (int k=0;k<64;k++) a += hT[tid*64+k]*Wfc[k];
    out[s0+tid] = a;
  }
}

extern "C" void kernel_launch(void* const* d_in, const int* in_sizes, int n_in,
                              void* d_out, int out_size, void* d_ws, size_t ws_size,
                              hipStream_t stream) {
  const float* x   = (const float*)d_in[0];
  // d_in[1], d_in[2] (N1, N2): structurally dead — sigmoid(N1@N2)>0 is all-ones.
  const float* W1  = (const float*)d_in[3];
  const float* b1  = (const float*)d_in[4];
  const float* W2  = (const float*)d_in[5];
  const float* b2  = (const float*)d_in[6];
  const float* Wih = (const float*)d_in[7];
  const float* Whh = (const float*)d_in[8];
  const float* bih = (const float*)d_in[9];
  const float* bhh = (const float*)d_in[10];
  const float* Wfc = (const float*)d_in[11];
  const float* bfc = (const float*)d_in[12];

  uint*  sxp = (uint*)d_ws;    // [48][13248][64] packed (bf16hi<<16)|bf16lo = 162.8 MB
  float* out = (float*)d_out;

  hipFuncSetAttribute((const void*)gcn_kernel, hipFuncAttributeMaxDynamicSharedMemorySize, GCN4_LDS_BYTES);

  gcn_kernel<<<dim3(NT, NB), 256, GCN4_LDS_BYTES, stream>>>(x, W1, b1, W2, b2, sxp);
  lstm6_kernel<<<SB16, 256, 0, stream>>>(sxp, Wih, Whh, bih, bhh, Wfc, bfc, out);
}

// Round 8
// 405.702 us; speedup vs baseline: 7.0344x; 1.0322x over previous
//
#include <hip/hip_runtime.h>
#include <math.h>

#define NB 64
#define NN 207
#define NT 48
#define NF 6
#define NH 64
#define NSEQ (NB*NN)        // 13248 = 828*16
#define NG   (NSEQ/16)      // 828 LSTM blocks of 16 seqs
#define TSTRIDE ((size_t)NSEQ*NH)   // u32 per t-plane of sxp

typedef short bf8_t __attribute__((ext_vector_type(8)));
typedef float f4_t  __attribute__((ext_vector_type(4)));
typedef unsigned short ushort;
typedef unsigned int uint;

__device__ __forceinline__ ushort bf16h(float x){
  uint u = __float_as_uint(x);
  return (ushort)((u + 0x7FFF + ((u>>16)&1)) >> 16);
}
__device__ __forceinline__ float bf16f(ushort h){
  return __uint_as_float((uint)h << 16);
}
__device__ __forceinline__ float fsig(float x){
  return __builtin_amdgcn_rcpf(1.0f + __expf(-x));
}
__device__ __forceinline__ float ftanh(float x){
  x = fminf(15.0f, fmaxf(-15.0f, x));
  float e = __expf(2.0f*x);
  return 1.0f - 2.0f*__builtin_amdgcn_rcpf(e + 1.0f);
}

// interchange: sxp[t][sg][64] u32, each = (bf16_hi<<16)|bf16_lo of h2 (row-major
// == MFMA A-fragment order for 16-seq groups: A[m=lane&15][k=quad*8+j])

// ---------------- GCN v5: atomic-storm fixes ----------------
#define HW 72
#define GCN5_LDS_BYTES (208*HW*2 + (NN*NF + NF*64 + 64 + 64 + 64 + 64 + 8)*4)

__global__ __launch_bounds__(256, 4) void gcn_kernel(
    const float* __restrict__ x, const float* __restrict__ W1, const float* __restrict__ b1,
    const float* __restrict__ W2, const float* __restrict__ b2, uint* __restrict__ sxp)
{
  extern __shared__ char smraw[];
  ushort* h1b = (ushort*)smraw;            // [208][72] bf16 (row 207 = zero pad)
  float*  xs  = (float*)(h1b + 208*HW);    // [207][6]
  float*  W1s = xs + NN*NF;                // [6][64]
  float*  b1s = W1s + NF*64;
  float*  b2s = b1s + 64;
  float*  S2  = b2s + 64;
  float*  r1  = S2 + 64;
  float*  xsA = r1 + 64;

  const int tid = threadIdx.x;
  const int t = blockIdx.x, b = blockIdx.y;
  const float inv = 1.0f/208.0f;
  const int l = tid & 63;
  const int w = __builtin_amdgcn_readfirstlane(tid >> 6);
  const int col = l & 15, q = l >> 4;
  const int cw = w*16 + col;

  if (tid < 64){ S2[tid]=0.f; r1[tid]=0.f; }
  if (tid < 8) xsA[tid]=0.f;
  if (tid < 72) h1b[207*HW + tid] = 0;
  __syncthreads();

  for (int i=tid;i<NF*64;i+=256) W1s[i]=W1[i];
  if (tid<64){ b1s[tid]=b1[tid]; b2s[tid]=b2[tid]; }
  {
    const float* xb = x + (size_t)b*NN*NT*NF + (size_t)t*NF;
    for (int i=tid;i<NN*NF;i+=256){ int n=i/NF, f=i-n*NF; xs[i] = xb[(size_t)n*NT*NF + f]; }
  }
  __syncthreads();

  // xsA: 48-thread reduction (8 partials per f -> 48 atomics over 6 addrs)
  if (tid < 48){
    int f = tid >> 3, p = tid & 7;
    float ps = 0.f;
    for (int n=p; n<NN; n+=8) ps += xs[n*NF+f];
    atomicAdd(&xsA[f], ps);
  }

  // W2 fragment loads (consumed after layer1; latency hidden)
  float wtmp[16];
  #pragma unroll
  for (int kc=0;kc<2;kc++)
    #pragma unroll
    for (int j=0;j<8;j++)
      wtmp[kc*8+j] = W2[(size_t)(kc*32 + q*8 + j)*64 + cw];
  __syncthreads();

  // ---- layer 1: ht is p-invariant -> hoist s1v, accumulate colsums in regs ----
  {
    const int ht4 = (tid & 15) * 4;
    const int nti = tid >> 4;
    float s1v[4];
    #pragma unroll
    for (int j=0;j<4;j++){
      float a = 0.f;
      #pragma unroll
      for (int f=0;f<NF;f++) a += xsA[f]*W1s[f*64 + ht4 + j];
      s1v[j] = a;
    }
    float cs0=0.f, cs1=0.f, cs2=0.f, cs3=0.f;
    #pragma unroll 1
    for (int p=0;p<4;p++){
      int nt = p*16 + nti;
      if (nt < 52){
        #pragma unroll
        for (int i=0;i<4;i++){
          int n = 4*nt+i;
          if (n < NN){
            float a0=0.f,a1=0.f,a2=0.f,a3=0.f;
            #pragma unroll
            for (int f=0;f<NF;f++){
              float xv = xs[n*NF+f];
              float4 wv = *(const float4*)&W1s[f*64 + ht4];
              a0+=xv*wv.x; a1+=xv*wv.y; a2+=xv*wv.z; a3+=xv*wv.w;
            }
            float v0=(a0+s1v[0])*inv + b1s[ht4+0]; v0 = v0>0.f?v0:0.f;
            float v1=(a1+s1v[1])*inv + b1s[ht4+1]; v1 = v1>0.f?v1:0.f;
            float v2=(a2+s1v[2])*inv + b1s[ht4+2]; v2 = v2>0.f?v2:0.f;
            float v3=(a3+s1v[3])*inv + b1s[ht4+3]; v3 = v3>0.f?v3:0.f;
            ushort4 hi;
            hi.x=bf16h(v0); hi.y=bf16h(v1); hi.z=bf16h(v2); hi.w=bf16h(v3);
            *(ushort4*)&h1b[n*HW + ht4] = hi;
            cs0+=v0; cs1+=v1; cs2+=v2; cs3+=v3;
          }
        }
      }
    }
    atomicAdd(&r1[ht4+0], cs0);
    atomicAdd(&r1[ht4+1], cs1);
    atomicAdd(&r1[ht4+2], cs2);
    atomicAdd(&r1[ht4+3], cs3);
  }
  __syncthreads();

  // S2 = r1 @ W2 (fp32 exact; 1 atomic/thread, 4-way)
  {
    int h = tid & 63, pp = tid >> 6;
    float ps = 0.f;
    #pragma unroll
    for (int k=0;k<16;k++) ps += r1[pp*16+k]*W2[(size_t)(pp*16+k)*64 + h];
    atomicAdd(&S2[h], ps);
  }

  // layer 2: single-bf16 MFMA
  bf8_t B2[2];
  #pragma unroll
  for (int kc=0;kc<2;kc++){
    bf8_t ph;
    #pragma unroll
    for (int j=0;j<8;j++) ph[j] = (short)bf16h(wtmp[kc*8+j]);
    B2[kc]=ph;
  }
  f4_t acc[13];
  #pragma unroll
  for (int mt=0;mt<13;mt++){ f4_t z; z[0]=0.f;z[1]=0.f;z[2]=0.f;z[3]=0.f; acc[mt]=z; }
  #pragma unroll 2
  for (int mt=0;mt<13;mt++){
    #pragma unroll
    for (int kc=0;kc<2;kc++){
      bf8_t ah = *(const bf8_t*)(h1b + (mt*16+col)*HW + kc*32 + q*8);
      acc[mt] = __builtin_amdgcn_mfma_f32_16x16x32_bf16(ah, B2[kc], acc[mt], 0,0,0);
    }
  }
  __syncthreads();   // S2 atomics + all h1 reads complete

  // epilogue: h2 -> packed u32 rows [t][b*207+n][cw]
  {
    const float s2v = S2[cw], b2v = b2s[cw];
    uint* obase = sxp + ((size_t)t*NSEQ + (size_t)b*NN)*NH + cw;
    #pragma unroll
    for (int mt=0;mt<13;mt++){
      #pragma unroll
      for (int r=0;r<4;r++){
        int n = mt*16 + q*4 + r;
        if (n < NN){
          float v = (acc[mt][r] + s2v)*inv + b2v;
          v = v>0.f ? v : 0.f;
          ushort hb = bf16h(v);
          ushort lb = bf16h(v - bf16f(hb));
          obase[(size_t)n*NH] = ((uint)hb<<16) | (uint)lb;
        }
      }
    }
  }
}

// ---------------- LSTM v7: x direct-from-global, u32 h plane, no spill ----------------
// 828 blocks x 256 thr. Wave w owns gate dims [16w,16w+16) x 4 types for the
// block's 16 seqs. x A-frags read straight from sxp (row-major == frag order),
// prefetched one step ahead. h: packed-u32 [16 s][68] double-buffered LDS
// (writes 2-way free, b128 reads ~4-way). 1 barrier/step.
#define HS 68

__global__ __launch_bounds__(256, 2) void lstm7_kernel(
    const uint* __restrict__ sxp,
    const float* __restrict__ Wih, const float* __restrict__ Whh,
    const float* __restrict__ bih, const float* __restrict__ bhh,
    const float* __restrict__ Wfc, const float* __restrict__ bfc, float* __restrict__ out)
{
  __shared__ uint hf[2][16*HS + 4];    // 8.7 KB

  const int tid = threadIdx.x;
  const int l = tid & 63;
  const int w = __builtin_amdgcn_readfirstlane(tid >> 6);
  const int col = l & 15, q = l >> 4;
  const int g = blockIdx.x;

  // B fragments: [ty][mat*2+kk]; mat 0 = Wih (x), 1 = Whh (h). 128 VGPRs.
  bf8_t Bh[4][4], Bl[4][4];
  #pragma unroll
  for (int mat=0; mat<2; mat++){
    const float* W = mat ? Whh : Wih;
    #pragma unroll
    for (int ty=0; ty<4; ty++){
      #pragma unroll
      for (int kk=0; kk<2; kk++){
        const float* wp = W + (size_t)(ty*64 + w*16 + col)*64 + kk*32 + q*8;
        bf8_t ph, pl;
        #pragma unroll
        for (int j=0;j<8;j++){
          float wv = wp[j];
          ushort hb = bf16h(wv);
          ph[j] = (short)hb;
          pl[j] = (short)bf16h(wv - bf16f(hb));
        }
        Bh[ty][mat*2+kk] = ph;
        Bl[ty][mat*2+kk] = pl;
      }
    }
  }
  float bias[4];
  #pragma unroll
  for (int ty=0;ty<4;ty++){
    int r = ty*64 + w*16 + col;
    bias[ty] = bih[r] + bhh[r];
  }
  float c[4];
  #pragma unroll
  for (int i=0;i<4;i++) c[i]=0.f;

  // zero h buffer 0
  for (int i=tid; i<16*HS; i+=256) hf[0][i] = 0;

  // x source: lane (col,q) reads u32[col*64 + kk*32 + q*8 + 0..7]
  const uint* xg = sxp + (size_t)g*1024 + (size_t)(col*64 + q*8);
  uint4 cA0, cA1, cB0, cB1;            // current x (kk0: A0,A1; kk1: B0,B1)
  cA0 = *(const uint4*)(xg);
  cA1 = *(const uint4*)(xg + 4);
  cB0 = *(const uint4*)(xg + 32);
  cB1 = *(const uint4*)(xg + 36);

  const int d = w*16 + col;            // owned h-dim
  const uint* hrd = &hf[0][0] + col*HS + q*8;   // read base (buf 0); buf1 = +16*HS+4
  __syncthreads();

  #pragma unroll 2
  for (int t=0; t<NT; t++){
    const int cur = t & 1;
    // unpack current x into frags
    bf8_t xh[2], xl[2];
    {
      uint u[8];
      u[0]=cA0.x;u[1]=cA0.y;u[2]=cA0.z;u[3]=cA0.w;u[4]=cA1.x;u[5]=cA1.y;u[6]=cA1.z;u[7]=cA1.w;
      #pragma unroll
      for (int j=0;j<8;j++){ xh[0][j]=(short)(u[j]>>16); xl[0][j]=(short)(u[j]&0xffff); }
      u[0]=cB0.x;u[1]=cB0.y;u[2]=cB0.z;u[3]=cB0.w;u[4]=cB1.x;u[5]=cB1.y;u[6]=cB1.z;u[7]=cB1.w;
      #pragma unroll
      for (int j=0;j<8;j++){ xh[1][j]=(short)(u[j]>>16); xl[1][j]=(short)(u[j]&0xffff); }
    }
    // prefetch x(t+1)
    if (t+1 < NT){
      const uint* xn = xg + (size_t)(t+1)*TSTRIDE;
      cA0 = *(const uint4*)(xn);
      cA1 = *(const uint4*)(xn + 4);
      cB0 = *(const uint4*)(xn + 32);
      cB1 = *(const uint4*)(xn + 36);
    }
    // h frags from LDS (buf cur)
    bf8_t hh[2], hl[2];
    {
      const uint* hb = hrd + (cur ? (16*HS+4) : 0);
      uint4 h0 = *(const uint4*)(hb);
      uint4 h1 = *(const uint4*)(hb + 4);
      uint4 h2 = *(const uint4*)(hb + 32);
      uint4 h3 = *(const uint4*)(hb + 36);
      uint u[8];
      u[0]=h0.x;u[1]=h0.y;u[2]=h0.z;u[3]=h0.w;u[4]=h1.x;u[5]=h1.y;u[6]=h1.z;u[7]=h1.w;
      #pragma unroll
      for (int j=0;j<8;j++){ hh[0][j]=(short)(u[j]>>16); hl[0][j]=(short)(u[j]&0xffff); }
      u[0]=h2.x;u[1]=h2.y;u[2]=h2.z;u[3]=h2.w;u[4]=h3.x;u[5]=h3.y;u[6]=h3.z;u[7]=h3.w;
      #pragma unroll
      for (int j=0;j<8;j++){ hh[1][j]=(short)(u[j]>>16); hl[1][j]=(short)(u[j]&0xffff); }
    }

    f4_t acc[4];
    #pragma unroll
    for (int ty=0;ty<4;ty++){ f4_t z; z[0]=bias[ty];z[1]=bias[ty];z[2]=bias[ty];z[3]=bias[ty]; acc[ty]=z; }
    #pragma unroll
    for (int kk=0;kk<2;kk++){
      #pragma unroll
      for (int ty=0;ty<4;ty++){
        acc[ty] = __builtin_amdgcn_mfma_f32_16x16x32_bf16(xh[kk], Bh[ty][kk],   acc[ty], 0,0,0);
        acc[ty] = __builtin_amdgcn_mfma_f32_16x16x32_bf16(xl[kk], Bh[ty][kk],   acc[ty], 0,0,0);
        acc[ty] = __builtin_amdgcn_mfma_f32_16x16x32_bf16(xh[kk], Bl[ty][kk],   acc[ty], 0,0,0);
        acc[ty] = __builtin_amdgcn_mfma_f32_16x16x32_bf16(hh[kk], Bh[ty][2+kk], acc[ty], 0,0,0);
        acc[ty] = __builtin_amdgcn_mfma_f32_16x16x32_bf16(hl[kk], Bh[ty][2+kk], acc[ty], 0,0,0);
        acc[ty] = __builtin_amdgcn_mfma_f32_16x16x32_bf16(hh[kk], Bl[ty][2+kk], acc[ty], 0,0,0);
      }
    }

    // update: C row (q*4+r) = seq, col = dim offset
    {
      uint* hw = &hf[cur^1][0];
      #pragma unroll
      for (int r=0;r<4;r++){
        float ig = fsig(acc[0][r]);
        float fg = fsig(acc[1][r]);
        float gt = ftanh(acc[2][r]);
        float og = fsig(acc[3][r]);
        float cc = fg*c[r] + ig*gt;
        c[r] = cc;
        float hv = og*ftanh(cc);
        int off = (q*4+r)*HS + d;
        if (t != NT-1){
          ushort hb2 = bf16h(hv);
          ushort lb2 = bf16h(hv - bf16f(hb2));
          hw[off] = ((uint)hb2<<16) | (uint)lb2;
        } else {
          hw[off] = __float_as_uint(hv);
        }
      }
    }
    __syncthreads();
  }

  // epilogue: out[seq] = h_T . W_fc + b_fc  (final h fp32 in hf[0])
  if (tid < 16){
    float a = bfc[0];
    #pragma unroll 8
    for (int k=0;k<64;k++) a += __uint_as_float(hf[0][tid*HS + k]) * Wfc[k];
    out[g*16 + tid] = a;
  }
}

extern "C" void kernel_launch(void* const* d_in, const int* in_sizes, int n_in,
                              void* d_out, int out_size, void* d_ws, size_t ws_size,
                              hipStream_t stream) {
  const float* x   = (const float*)d_in[0];
  // d_in[1], d_in[2] (N1, N2): structurally dead — sigmoid(N1@N2)>0 is all-ones.
  const float* W1  = (const float*)d_in[3];
  const float* b1  = (const float*)d_in[4];
  const float* W2  = (const float*)d_in[5];
  const float* b2  = (const float*)d_in[6];
  const float* Wih = (const float*)d_in[7];
  const float* Whh = (const float*)d_in[8];
  const float* bih = (const float*)d_in[9];
  const float* bhh = (const float*)d_in[10];
  const float* Wfc = (const float*)d_in[11];
  const float* bfc = (const float*)d_in[12];

  uint*  sxp = (uint*)d_ws;    // [48][13248][64] packed (bf16hi<<16)|bf16lo = 162.8 MB
  float* out = (float*)d_out;

  hipFuncSetAttribute((const void*)gcn_kernel, hipFuncAttributeMaxDynamicSharedMemorySize, GCN5_LDS_BYTES);

  gcn_kernel<<<dim3(NT, NB), 256, GCN5_LDS_BYTES, stream>>>(x, W1, b1, W2, b2, sxp);
  lstm7_kernel<<<NG, 256, 0, stream>>>(sxp, Wih, Whh, bih, bhh, Wfc, bfc, out);
}

// Round 9
// 356.497 us; speedup vs baseline: 8.0053x; 1.1380x over previous
//
#include <hip/hip_runtime.h>
#include <math.h>

#define NB 64
#define NN 207
#define NT 48
#define NF 6
#define NH 64
#define NSEQ (NB*NN)        // 13248 = 828*16
#define NG   (NSEQ/16)      // 828 LSTM blocks of 16 seqs
#define TSTRIDE ((size_t)NSEQ*NH)   // u32 per t-plane of sxp

typedef short bf8_t __attribute__((ext_vector_type(8)));
typedef float f4_t  __attribute__((ext_vector_type(4)));
typedef unsigned short ushort;
typedef unsigned int uint;

__device__ __forceinline__ ushort bf16h(float x){
  uint u = __float_as_uint(x);
  return (ushort)((u + 0x7FFF + ((u>>16)&1)) >> 16);
}
__device__ __forceinline__ float bf16f(ushort h){
  return __uint_as_float((uint)h << 16);
}
__device__ __forceinline__ float fsig(float x){
  return __builtin_amdgcn_rcpf(1.0f + __expf(-x));
}
__device__ __forceinline__ float ftanh(float x){
  x = fminf(15.0f, fmaxf(-15.0f, x));
  float e = __expf(2.0f*x);
  return 1.0f - 2.0f*__builtin_amdgcn_rcpf(e + 1.0f);
}

// interchange: sxp[t][sg][64] u32, each = (bf16_hi<<16)|bf16_lo of h2 (row-major
// == MFMA A-fragment order for 16-seq groups)

// ---------------- GCN v6: 4 t-planes per block ----------------
// grid (12, 64): block = (t-group of 4, batch b). Amortizes all staging 4x,
// x reads become 96B-contiguous, 2.5 barriers/t. Per-t S2/r1 slices.
#define HW 72
#define XS4 28   // xs row stride (floats): 16B-aligned, bank-safe (<=2-way)
#define GCN6_LDS_BYTES (208*HW*2 + (207*XS4 + NF*64 + 64 + 64 + 256 + 256 + 32)*4)

__global__ __launch_bounds__(256, 2) void gcn_kernel(
    const float* __restrict__ x, const float* __restrict__ W1, const float* __restrict__ b1,
    const float* __restrict__ W2, const float* __restrict__ b2, uint* __restrict__ sxp)
{
  extern __shared__ char smraw[];
  ushort* h1b = (ushort*)smraw;            // [208][72] bf16 (row 207 = zero pad)
  float*  xs4 = (float*)(h1b + 208*HW);    // [207][28] (24 used: 4 t x 6 f)
  float*  W1s = xs4 + 207*XS4;             // [6][64]
  float*  b1s = W1s + NF*64;               // 64
  float*  b2s = b1s + 64;                  // 64
  float*  S2_ = b2s + 64;                  // [4][64]
  float*  r1_ = S2_ + 256;                 // [4][64]
  float*  xsA = r1_ + 256;                 // [4][8]

  const int tid = threadIdx.x;
  const int tg = blockIdx.x, b = blockIdx.y;
  const float inv = 1.0f/208.0f;
  const int l = tid & 63;
  const int w = __builtin_amdgcn_readfirstlane(tid >> 6);
  const int col = l & 15, q = l >> 4;
  const int cw = w*16 + col;

  // zero per-t accumulators + pad row
  S2_[tid] = 0.f;                  // 256 exactly
  r1_[tid] = 0.f;
  if (tid < 32) xsA[tid] = 0.f;
  if (tid < 72) h1b[207*HW + tid] = 0;

  // stage W1, biases, x (4 t-planes: 24 contiguous floats per n)
  for (int i=tid;i<NF*64;i+=256) W1s[i]=W1[i];
  if (tid<64){ b1s[tid]=b1[tid]; b2s[tid]=b2[tid]; }
  {
    const float* xb = x + (size_t)b*NN*(NT*NF) + (size_t)tg*24;
    for (int i=tid; i<207*6; i+=256){
      int n = i/6, c = (i - n*6)*4;
      *(float4*)&xs4[n*XS4 + c] = *(const float4*)&xb[(size_t)n*(NT*NF) + c];
    }
  }
  __syncthreads();

  // xsA[tt][f] = sum_n x: 192 threads, 8 partials each
  if (tid < 192){
    int tt = tid/48, rem = tid - tt*48, f = rem>>3, p = rem&7;
    float ps = 0.f;
    for (int n=p; n<NN; n+=8) ps += xs4[n*XS4 + tt*6 + f];
    atomicAdd(&xsA[tt*8+f], ps);
  }

  // W2 B-fragments (loaded once for all 4 t)
  float wtmp[16];
  #pragma unroll
  for (int kc=0;kc<2;kc++)
    #pragma unroll
    for (int j=0;j<8;j++)
      wtmp[kc*8+j] = W2[(size_t)(kc*32 + q*8 + j)*64 + cw];
  bf8_t B2[2];
  #pragma unroll
  for (int kc=0;kc<2;kc++){
    bf8_t ph;
    #pragma unroll
    for (int j=0;j<8;j++) ph[j] = (short)bf16h(wtmp[kc*8+j]);
    B2[kc]=ph;
  }
  __syncthreads();

  const int ht4 = (tid & 15) * 4;
  const int nti = tid >> 4;

  #pragma unroll 1
  for (int tt=0; tt<4; tt++){
    const int t = tg*4 + tt;
    // ---- layer 1: h1 = relu((x@W1 + S1)/208 + b1) -> bf16 plane + r1 ----
    {
      float s1v[4];
      #pragma unroll
      for (int j=0;j<4;j++){
        float a = 0.f;
        #pragma unroll
        for (int f=0;f<NF;f++) a += xsA[tt*8+f]*W1s[f*64 + ht4 + j];
        s1v[j] = a;
      }
      float cs0=0.f, cs1=0.f, cs2=0.f, cs3=0.f;
      #pragma unroll 1
      for (int p=0;p<4;p++){
        int nt = p*16 + nti;
        if (nt < 52){
          #pragma unroll
          for (int i=0;i<4;i++){
            int n = 4*nt+i;
            if (n < NN){
              float a0=0.f,a1=0.f,a2=0.f,a3=0.f;
              #pragma unroll
              for (int f=0;f<NF;f++){
                float xv = xs4[n*XS4 + tt*6 + f];
                float4 wv = *(const float4*)&W1s[f*64 + ht4];
                a0+=xv*wv.x; a1+=xv*wv.y; a2+=xv*wv.z; a3+=xv*wv.w;
              }
              float v0=(a0+s1v[0])*inv + b1s[ht4+0]; v0 = v0>0.f?v0:0.f;
              float v1=(a1+s1v[1])*inv + b1s[ht4+1]; v1 = v1>0.f?v1:0.f;
              float v2=(a2+s1v[2])*inv + b1s[ht4+2]; v2 = v2>0.f?v2:0.f;
              float v3=(a3+s1v[3])*inv + b1s[ht4+3]; v3 = v3>0.f?v3:0.f;
              ushort4 hi;
              hi.x=bf16h(v0); hi.y=bf16h(v1); hi.z=bf16h(v2); hi.w=bf16h(v3);
              *(ushort4*)&h1b[n*HW + ht4] = hi;
              cs0+=v0; cs1+=v1; cs2+=v2; cs3+=v3;
            }
          }
        }
      }
      atomicAdd(&r1_[tt*64+ht4+0], cs0);
      atomicAdd(&r1_[tt*64+ht4+1], cs1);
      atomicAdd(&r1_[tt*64+ht4+2], cs2);
      atomicAdd(&r1_[tt*64+ht4+3], cs3);
    }
    __syncthreads();

    // ---- S2 = r1 @ W2 (fp32 exact) ----
    {
      int h = tid & 63, pp = tid >> 6;
      float ps = 0.f;
      #pragma unroll
      for (int k=0;k<16;k++) ps += r1_[tt*64+pp*16+k]*W2[(size_t)(pp*16+k)*64 + h];
      atomicAdd(&S2_[tt*64+h], ps);
    }

    // ---- layer 2: single-bf16 MFMA ----
    f4_t acc[13];
    #pragma unroll
    for (int mt=0;mt<13;mt++){ f4_t z; z[0]=0.f;z[1]=0.f;z[2]=0.f;z[3]=0.f; acc[mt]=z; }
    #pragma unroll 2
    for (int mt=0;mt<13;mt++){
      #pragma unroll
      for (int kc=0;kc<2;kc++){
        bf8_t ah = *(const bf8_t*)(h1b + (mt*16+col)*HW + kc*32 + q*8);
        acc[mt] = __builtin_amdgcn_mfma_f32_16x16x32_bf16(ah, B2[kc], acc[mt], 0,0,0);
      }
    }
    __syncthreads();   // S2 atomics + all h1 reads complete (h1b free for tt+1)

    // ---- epilogue: h2 -> packed u32 rows [t][b*207+n][cw] ----
    {
      const float s2v = S2_[tt*64+cw], b2v = b2s[cw];
      uint* obase = sxp + ((size_t)t*NSEQ + (size_t)b*NN)*NH + cw;
      #pragma unroll
      for (int mt=0;mt<13;mt++){
        #pragma unroll
        for (int r=0;r<4;r++){
          int n = mt*16 + q*4 + r;
          if (n < NN){
            float v = (acc[mt][r] + s2v)*inv + b2v;
            v = v>0.f ? v : 0.f;
            ushort hb = bf16h(v);
            ushort lb = bf16h(v - bf16f(hb));
            obase[(size_t)n*NH] = ((uint)hb<<16) | (uint)lb;
          }
        }
      }
    }
  }
}

// ---------------- LSTM v8: lstm7 with the spill fix ----------------
// __launch_bounds__(256,1): gfx950 unified VGPR/AGPR budget becomes 512/wave,
// so the 128-VGPR B-frags + working set fit in arch regs (no scratch).
// Expected ~220 total -> still 2 blocks/CU at runtime.
#define HS 68

__global__ __launch_bounds__(256, 1) void lstm8_kernel(
    const uint* __restrict__ sxp,
    const float* __restrict__ Wih, const float* __restrict__ Whh,
    const float* __restrict__ bih, const float* __restrict__ bhh,
    const float* __restrict__ Wfc, const float* __restrict__ bfc, float* __restrict__ out)
{
  __shared__ uint hf[2][16*HS + 4];    // 8.7 KB

  const int tid = threadIdx.x;
  const int l = tid & 63;
  const int w = __builtin_amdgcn_readfirstlane(tid >> 6);
  const int col = l & 15, q = l >> 4;
  const int g = blockIdx.x;

  // B fragments: [ty][mat*2+kk]; mat 0 = Wih (x), 1 = Whh (h). 128 VGPRs.
  bf8_t Bh[4][4], Bl[4][4];
  #pragma unroll
  for (int mat=0; mat<2; mat++){
    const float* W = mat ? Whh : Wih;
    #pragma unroll
    for (int ty=0; ty<4; ty++){
      #pragma unroll
      for (int kk=0; kk<2; kk++){
        const float* wp = W + (size_t)(ty*64 + w*16 + col)*64 + kk*32 + q*8;
        bf8_t ph, pl;
        #pragma unroll
        for (int j=0;j<8;j++){
          float wv = wp[j];
          ushort hb = bf16h(wv);
          ph[j] = (short)hb;
          pl[j] = (short)bf16h(wv - bf16f(hb));
        }
        Bh[ty][mat*2+kk] = ph;
        Bl[ty][mat*2+kk] = pl;
      }
    }
  }
  float bias[4];
  #pragma unroll
  for (int ty=0;ty<4;ty++){
    int r = ty*64 + w*16 + col;
    bias[ty] = bih[r] + bhh[r];
  }
  float c[4];
  #pragma unroll
  for (int i=0;i<4;i++) c[i]=0.f;

  // zero h buffer 0
  for (int i=tid; i<16*HS; i+=256) hf[0][i] = 0;

  // x source: lane (col,q) reads u32[col*64 + kk*32 + q*8 + 0..7]
  const uint* xg = sxp + (size_t)g*1024 + (size_t)(col*64 + q*8);
  uint4 cA0, cA1, cB0, cB1;
  cA0 = *(const uint4*)(xg);
  cA1 = *(const uint4*)(xg + 4);
  cB0 = *(const uint4*)(xg + 32);
  cB1 = *(const uint4*)(xg + 36);

  const int d = w*16 + col;
  const uint* hrd = &hf[0][0] + col*HS + q*8;
  __syncthreads();

  #pragma unroll 2
  for (int t=0; t<NT; t++){
    const int cur = t & 1;
    bf8_t xh[2], xl[2];
    {
      uint u[8];
      u[0]=cA0.x;u[1]=cA0.y;u[2]=cA0.z;u[3]=cA0.w;u[4]=cA1.x;u[5]=cA1.y;u[6]=cA1.z;u[7]=cA1.w;
      #pragma unroll
      for (int j=0;j<8;j++){ xh[0][j]=(short)(u[j]>>16); xl[0][j]=(short)(u[j]&0xffff); }
      u[0]=cB0.x;u[1]=cB0.y;u[2]=cB0.z;u[3]=cB0.w;u[4]=cB1.x;u[5]=cB1.y;u[6]=cB1.z;u[7]=cB1.w;
      #pragma unroll
      for (int j=0;j<8;j++){ xh[1][j]=(short)(u[j]>>16); xl[1][j]=(short)(u[j]&0xffff); }
    }
    if (t+1 < NT){
      const uint* xn = xg + (size_t)(t+1)*TSTRIDE;
      cA0 = *(const uint4*)(xn);
      cA1 = *(const uint4*)(xn + 4);
      cB0 = *(const uint4*)(xn + 32);
      cB1 = *(const uint4*)(xn + 36);
    }
    bf8_t hh[2], hl[2];
    {
      const uint* hb = hrd + (cur ? (16*HS+4) : 0);
      uint4 h0 = *(const uint4*)(hb);
      uint4 h1 = *(const uint4*)(hb + 4);
      uint4 h2 = *(const uint4*)(hb + 32);
      uint4 h3 = *(const uint4*)(hb + 36);
      uint u[8];
      u[0]=h0.x;u[1]=h0.y;u[2]=h0.z;u[3]=h0.w;u[4]=h1.x;u[5]=h1.y;u[6]=h1.z;u[7]=h1.w;
      #pragma unroll
      for (int j=0;j<8;j++){ hh[0][j]=(short)(u[j]>>16); hl[0][j]=(short)(u[j]&0xffff); }
      u[0]=h2.x;u[1]=h2.y;u[2]=h2.z;u[3]=h2.w;u[4]=h3.x;u[5]=h3.y;u[6]=h3.z;u[7]=h3.w;
      #pragma unroll
      for (int j=0;j<8;j++){ hh[1][j]=(short)(u[j]>>16); hl[1][j]=(short)(u[j]&0xffff); }
    }

    f4_t acc[4];
    #pragma unroll
    for (int ty=0;ty<4;ty++){ f4_t z; z[0]=bias[ty];z[1]=bias[ty];z[2]=bias[ty];z[3]=bias[ty]; acc[ty]=z; }
    #pragma unroll
    for (int kk=0;kk<2;kk++){
      #pragma unroll
      for (int ty=0;ty<4;ty++){
        acc[ty] = __builtin_amdgcn_mfma_f32_16x16x32_bf16(xh[kk], Bh[ty][kk],   acc[ty], 0,0,0);
        acc[ty] = __builtin_amdgcn_mfma_f32_16x16x32_bf16(xl[kk], Bh[ty][kk],   acc[ty], 0,0,0);
        acc[ty] = __builtin_amdgcn_mfma_f32_16x16x32_bf16(xh[kk], Bl[ty][kk],   acc[ty], 0,0,0);
        acc[ty] = __builtin_amdgcn_mfma_f32_16x16x32_bf16(hh[kk], Bh[ty][2+kk], acc[ty], 0,0,0);
        acc[ty] = __builtin_amdgcn_mfma_f32_16x16x32_bf16(hl[kk], Bh[ty][2+kk], acc[ty], 0,0,0);
        acc[ty] = __builtin_amdgcn_mfma_f32_16x16x32_bf16(hh[kk], Bl[ty][2+kk], acc[ty], 0,0,0);
      }
    }

    {
      uint* hw = &hf[cur^1][0];
      #pragma unroll
      for (int r=0;r<4;r++){
        float ig = fsig(acc[0][r]);
        float fg = fsig(acc[1][r]);
        float gt = ftanh(acc[2][r]);
        float og = fsig(acc[3][r]);
        float cc = fg*c[r] + ig*gt;
        c[r] = cc;
        float hv = og*ftanh(cc);
        int off = (q*4+r)*HS + d;
        if (t != NT-1){
          ushort hb2 = bf16h(hv);
          ushort lb2 = bf16h(hv - bf16f(hb2));
          hw[off] = ((uint)hb2<<16) | (uint)lb2;
        } else {
          hw[off] = __float_as_uint(hv);
        }
      }
    }
    __syncthreads();
  }

  // epilogue: out[seq] = h_T . W_fc + b_fc  (final h fp32 in hf[NT&1])
  if (tid < 16){
    float a = bfc[0];
    const uint* hT = &hf[NT&1][0];
    #pragma unroll 8
    for (int k=0;k<64;k++) a += __uint_as_float(hT[tid*HS + k]) * Wfc[k];
    out[g*16 + tid] = a;
  }
}

extern "C" void kernel_launch(void* const* d_in, const int* in_sizes, int n_in,
                              void* d_out, int out_size, void* d_ws, size_t ws_size,
                              hipStream_t stream) {
  const float* x   = (const float*)d_in[0];
  // d_in[1], d_in[2] (N1, N2): structurally dead — sigmoid(N1@N2)>0 is all-ones.
  const float* W1  = (const float*)d_in[3];
  const float* b1  = (const float*)d_in[4];
  const float* W2  = (const float*)d_in[5];
  const float* b2  = (const float*)d_in[6];
  const float* Wih = (const float*)d_in[7];
  const float* Whh = (const float*)d_in[8];
  const float* bih = (const float*)d_in[9];
  const float* bhh = (const float*)d_in[10];
  const float* Wfc = (const float*)d_in[11];
  const float* bfc = (const float*)d_in[12];

  uint*  sxp = (uint*)d_ws;    // [48][13248][64] packed (bf16hi<<16)|bf16lo = 162.8 MB
  float* out = (float*)d_out;

  hipFuncSetAttribute((const void*)gcn_kernel, hipFuncAttributeMaxDynamicSharedMemorySize, GCN6_LDS_BYTES);

  gcn_kernel<<<dim3(NT/4, NB), 256, GCN6_LDS_BYTES, stream>>>(x, W1, b1, W2, b2, sxp);
  lstm8_kernel<<<NG, 256, 0, stream>>>(sxp, Wih, Whh, bih, bhh, Wfc, bfc, out);
}